// Round 5
// baseline (1095.133 us; speedup 1.0000x reference)
//
#include <hip/hip_runtime.h>
#include <hip/hip_bf16.h>

#define NEDGE 640000
#define NMAX  40000
#define SB    40      // scan blocks
#define PRB   256     // parallel pool-reduce blocks (1 channel each)
#define EBLK  512     // edge-compact blocks (128 thr)
#define FB    1280    // fill blocks (128 thr each)
#define LIN1B 64      // lin1 partial blocks
#define GRB   16      // gemm rows per block (r2-best shape: 128 thr, 10.2 KB LDS, ~15 blocks/CU)
#define HTS   20      // ht row stride (GRB+4, multiple of 4 for float4 reads)
#define TKB   32      // fused top-k blocks
#define GHN   5632    // global hist ints (2048+2048+1024+256+256)
#define GBMAX 2048    // scr row stride (>= max gemm blocks per layer = 2000)

// ---------------------------------------------------------------- helpers
__device__ inline unsigned orderKey(float s) {
    unsigned b = __float_as_uint(s);
    return (b & 0x80000000u) ? ~b : (b | 0x80000000u);
}

// ballot-dedup LDS histogram insert: O(1) atomics per distinct bin per wave
__device__ inline void histAdd(int* sh, int bin, bool act, int nbits) {
    unsigned long long mm = __ballot(act);
    for (int b = 0; b < nbits; b++) {
        unsigned long long bal = __ballot(act && ((bin >> b) & 1));
        mm &= ((bin >> b) & 1) ? bal : ~bal;
    }
    if (act) {
        int lane = threadIdx.x & 63;
        int leader = __ffsll(mm) - 1;
        if (lane == leader) atomicAdd(&sh[bin], __popcll(mm));
    }
}

// grid barrier for co-resident blocks (fresh counter per use, zeroed in k_init)
__device__ inline void gridbar(int* ctr, int target) {
    __syncthreads();
    if (threadIdx.x == 0) {
        __threadfence();
        __hip_atomic_fetch_add(ctr, 1, __ATOMIC_RELEASE, __HIP_MEMORY_SCOPE_AGENT);
        while (__hip_atomic_load(ctr, __ATOMIC_ACQUIRE, __HIP_MEMORY_SCOPE_AGENT) < target)
            __builtin_amdgcn_s_sleep(1);
        __threadfence();
    }
    __syncthreads();
}

__device__ inline int waveScanIncl(int v) {
    int lane = threadIdx.x & 63;
    #pragma unroll
    for (int off = 1; off < 64; off <<= 1) {
        int o = __shfl_up(v, off);
        if (lane >= off) v += o;
    }
    return v;
}

// find bin d such that suffix-sum S[d] >= rem > S[d+1] over 2048 bins, via shfl prefix scan.
// outR = rem - S[d+1]; outCnt = h[d]. 1024 threads, 2 bins/thread.
__device__ inline void selScan2048(const int* gh, int rem, int* outD, int* outR, int* outCnt) {
    __shared__ int wtot[16];
    __shared__ int s_T;
    int t = threadIdx.x, lane = t & 63, wid = t >> 6;
    int a0 = gh[2*t], a1 = gh[2*t+1];
    int s  = a0 + a1;
    int ws = waveScanIncl(s);
    if (lane == 63) wtot[wid] = ws;
    __syncthreads();
    if (t < 16) {
        int v = wtot[t];
        #pragma unroll
        for (int off = 1; off < 16; off <<= 1) { int o = __shfl_up(v, off); if (lane >= off) v += o; }
        wtot[t] = v;
        if (t == 15) s_T = v;
    }
    __syncthreads();
    int base = (wid > 0) ? wtot[wid-1] : 0;
    int inclPair = base + ws;          // inclusive prefix through bin 2t+1
    int P1 = inclPair - a1;            // exclusive prefix of bin 2t+1
    int P0 = P1 - a0;                  // exclusive prefix of bin 2t
    int Q = s_T - rem;
    if (a0 > 0 && P0 <= Q && Q < P0 + a0) { *outD = 2*t;   *outR = a0 - (Q - P0); *outCnt = a0; }
    if (a1 > 0 && P1 <= Q && Q < P1 + a1) { *outD = 2*t+1; *outR = a1 - (Q - P1); *outCnt = a1; }
    __syncthreads();
}

// same over 1024 bins, 1 bin/thread
__device__ inline void selScan1024(const int* gh, int rem, int* outD, int* outR, int* outCnt) {
    __shared__ int wtot[16];
    __shared__ int s_T;
    int t = threadIdx.x, lane = t & 63, wid = t >> 6;
    int a0 = gh[t];
    int ws = waveScanIncl(a0);
    if (lane == 63) wtot[wid] = ws;
    __syncthreads();
    if (t < 16) {
        int v = wtot[t];
        #pragma unroll
        for (int off = 1; off < 16; off <<= 1) { int o = __shfl_up(v, off); if (lane >= off) v += o; }
        wtot[t] = v;
        if (t == 15) s_T = v;
    }
    __syncthreads();
    int base = (wid > 0) ? wtot[wid-1] : 0;
    int P0 = base + ws - a0;           // exclusive prefix
    int Q = s_T - rem;
    if (a0 > 0 && P0 <= Q && Q < P0 + a0) { *outD = t; *outR = a0 - (Q - P0); *outCnt = a0; }
    __syncthreads();
}

__device__ inline void prefixSel256(int* lh, const int* gh, int rem, int* outD, int* outR) {
    int t = threadIdx.x;
    if (t < 256) lh[t] = gh[t];
    __syncthreads();
    for (int off = 1; off < 256; off <<= 1) {
        int v = 0;
        if (t < 256) v = lh[t] + ((t >= off) ? lh[t-off] : 0);
        __syncthreads();
        if (t < 256) lh[t] = v;
        __syncthreads();
    }
    if (t < 256) {
        int P = lh[t], Pp = (t == 0) ? 0 : lh[t-1];
        if (P >= rem && Pp < rem) { *outD = t; *outR = rem - Pp; }
    }
    __syncthreads();
}

// parallel pool-stat reduce: one block per channel, coalesced reads of
// transposed scr[ch*GBMAX + r] -> rbuf[L*256 + ch]
__device__ inline void poolReduceT(const float* __restrict__ scr, float* __restrict__ rbuf,
                                   int gbP, int L, int ch) {
    int t = threadIdx.x;
    bool isMax = ch < 128;
    float acc = isMax ? -3.402823e38f : 0.f;
    for (int r = t; r < gbP; r += 256) {
        float v = scr[(size_t)ch*GBMAX + r];
        acc = isMax ? fmaxf(acc, v) : (acc + v);
    }
    __shared__ float red[256];
    red[t] = acc; __syncthreads();
    for (int st = 128; st > 0; st >>= 1) {
        if (t < st) red[t] = isMax ? fmaxf(red[t], red[t+st]) : (red[t] + red[t+st]);
        __syncthreads();
    }
    if (t == 0) rbuf[L*256 + ch] = red[0];
}

__device__ const float c_invk[10] = {
    1.0f/32000.0f, 1.0f/25600.0f, 1.0f/20480.0f, 1.0f/16384.0f, 1.0f/13108.0f,
    1.0f/10487.0f, 1.0f/8390.0f,  1.0f/6712.0f,  1.0f/5370.0f,  1.0f/4296.0f };

// ---------------------------------------------------------------- init (+ layer-0 degree count + ranks)
__global__ void k_init(const int* __restrict__ eidx, int* __restrict__ esrc,
                       int* __restrict__ edst, int* __restrict__ erank,
                       const float* __restrict__ poolp,
                       float* __restrict__ rbuf, float* __restrict__ pnorm,
                       int* __restrict__ ecnt, int* __restrict__ degA,
                       int* __restrict__ tkc) {
    int b = blockIdx.x, t = threadIdx.x;
    if (b < 10) {
        rbuf[b*256 + t] = (t < 128) ? -3.402823e38f : 0.0f;
        __shared__ float red[256];
        float v = 0.0f;
        if (t < 128) { float pv = poolp[b*128 + t]; v = pv*pv; }
        red[t] = v; __syncthreads();
        for (int s = 128; s > 0; s >>= 1) { if (t < s) red[t] += red[t+s]; __syncthreads(); }
        if (t == 0) pnorm[b] = sqrtf(red[0]);
    }
    if (b == 10 && t < 16) ecnt[t] = (t == 0) ? NEDGE : 0;
    if (b == 11 && t < 64) tkc[t] = 0;
    int e = b*256 + t;
    if (e < NEDGE) {
        int d = eidx[NEDGE + e];
        esrc[e] = eidx[e]; edst[e] = d;
        erank[e] = atomicAdd(&degA[d], 1);
    }
}

// ---------------------------------------------------------------- per-chunk sums (kernel-boundary replaces barrier)
__global__ __launch_bounds__(256) void k_presum(const int* __restrict__ deg,
                                                int* __restrict__ lbsum,
                                                int n, int chunk) {
    int b = blockIdx.x, t = threadIdx.x;
    __shared__ int red[256];
    int start = b*chunk, end = min(start + chunk, n);
    int s = 0;
    for (int i = start + t; i < end; i += 256) s += deg[i];
    red[t] = s; __syncthreads();
    for (int st = 128; st > 0; st >>= 1) { if (t < st) red[t] += red[t+st]; __syncthreads(); }
    if (t == 0) lbsum[b] = red[0];
}

// ---------------------------------------------------------------- scan + parallel pool reduce
// blocks [0,SB): scan; blocks [SB,SB+PRB): reduce previous layer's pool scratch (1 channel each)
__global__ void k_scan(const int* __restrict__ deg,
                       int* __restrict__ offs, float* __restrict__ dinv,
                       int* __restrict__ ghist, int* __restrict__ selbuf,
                       const int* __restrict__ lbsum,
                       const float* __restrict__ scr, float* __restrict__ rbuf,
                       int n, int chunk, int gbP, int prevL) {
    int b = blockIdx.x, t = threadIdx.x, lane = t & 63, wid = t >> 6;
    if (b >= SB) {
        if (gbP > 0) poolReduceT(scr, rbuf, gbP, prevL, b - SB);
        return;
    }
    __shared__ int s_excl;
    __shared__ int wsum[4];
    __shared__ int s_carry;
    __shared__ int s_sums[SB];
    if (b == 0) {
        for (int jj = t; jj < GHN; jj += 256) ghist[jj] = 0;
        if (t == 0) { selbuf[2] = 0; selbuf[5] = 0; }
    }
    if (t < SB) s_sums[t] = lbsum[t];
    __syncthreads();
    if (t == 0) {
        int excl = 0;
        for (int p = 0; p < b; p++) excl += s_sums[p];
        s_excl = excl;
    }
    __syncthreads();
    if (t == 0) s_carry = s_excl;
    __syncthreads();
    int start = b*chunk, end = min(start + chunk, n);
    for (int base = start; base < end; base += 256) {
        int i = base + t;
        int d = (i < end) ? deg[i] : 0;
        int incl = d;
        for (int off = 1; off < 64; off <<= 1) {
            int o = __shfl_up(incl, off);
            if (lane >= off) incl += o;
        }
        if (lane == 63) wsum[wid] = incl;
        __syncthreads();
        if (t == 0) { int c = s_carry; for (int w = 0; w < 4; w++) { int tmp = wsum[w]; wsum[w] = c; c += tmp; } s_carry = c; }
        __syncthreads();
        int p = wsum[wid] + incl - d;
        if (i < end) {
            offs[i] = p;
            dinv[i] = (d > 0) ? 1.0f/sqrtf((float)d) : 0.0f;
        }
        __syncthreads();
    }
}

// ---------------------------------------------------------------- slim CSR fill (rank-based, no atomics, no LDS)
__global__ __launch_bounds__(128) void k_fill(const int* __restrict__ esrc, const int* __restrict__ edst,
                                              const int* __restrict__ erank, const int* __restrict__ offs,
                                              int* __restrict__ csr, const int* __restrict__ ecnt) {
    int ec = *ecnt;
    for (int e = blockIdx.x*128 + threadIdx.x; e < ec; e += FB*128)
        csr[offs[edst[e]] + erank[e]] = esrc[e];
}

// ---------------------------------------------------------------- layer-0 fused node update
__global__ __launch_bounds__(128) void k_gather0(
    const float* __restrict__ x, const float* __restrict__ W1, const float* __restrict__ V1,
    const float* __restrict__ convb,
    const float* __restrict__ bng, const float* __restrict__ bnb,
    const float* __restrict__ bnm, const float* __restrict__ bnv,
    const float* __restrict__ poolp, const float* __restrict__ pnorm,
    const float* __restrict__ prelua,
    const int* __restrict__ offs, const int* __restrict__ deg, const float* __restrict__ dinv,
    const int* __restrict__ csr,
    float* __restrict__ AGG, float* __restrict__ score, unsigned* __restrict__ keys) {
    int v = blockIdx.x, j = threadIdx.x;
    __shared__ float red[128];
    int off = offs[v], dg = deg[v];
    float accs = 0.0f;
    for (int c = j; c < dg; c += 128) { int s = csr[off + c]; accs += x[s]*dinv[s]; }
    red[j] = accs; __syncthreads();
    for (int st = 64; st > 0; st >>= 1) { if (j < st) red[j] += red[j+st]; __syncthreads(); }
    float aggs = red[0] * dinv[v];
    __syncthreads();
    float h2 = aggs*W1[j] + x[v]*V1[j] + convb[j];
    h2 = fmaxf(h2, 0.0f);
    float scale = bng[j] / sqrtf(bnv[j] + 1e-5f);
    h2 = (h2 - bnm[j])*scale + bnb[j];
    float a = prelua[0];
    h2 = (h2 > 0.0f) ? h2 : a*h2;
    AGG[v*128 + j] = h2;
    red[j] = h2 * poolp[j]; __syncthreads();
    for (int st = 64; st > 0; st >>= 1) { if (j < st) red[j] += red[j+st]; __syncthreads(); }
    if (j == 0) {
        float sc = tanhf(red[0] / pnorm[0]);
        score[v] = sc;
        keys[v]  = orderKey(sc);
    }
}

// ---------------------------------------------------------------- generic fused gather + update + score
__global__ __launch_bounds__(128) void k_gather(
    const float* __restrict__ HW, float* __restrict__ AGG,
    const int* __restrict__ offs, const int* __restrict__ deg, const float* __restrict__ dinv,
    const int* __restrict__ csr,
    const float* __restrict__ bng, const float* __restrict__ bnb,
    const float* __restrict__ bnm, const float* __restrict__ bnv,
    const float* __restrict__ poolp, const float* __restrict__ pnorm,
    const float* __restrict__ prelua,
    float* __restrict__ score, unsigned* __restrict__ keys, int layer) {
    int v = blockIdx.x, j = threadIdx.x;
    __shared__ int   s_src[128];
    __shared__ float s_dv[128];
    __shared__ float red[128];
    int off = offs[v], dg = deg[v];
    float acc = 0.0f;
    for (int base = 0; base < dg; base += 128) {
        int cnt = min(128, dg - base);
        if (j < cnt) { int s = csr[off + base + j]; s_src[j] = s; s_dv[j] = dinv[s]; }
        __syncthreads();
        for (int c = 0; c < cnt; c++) acc += HW[s_src[c]*128 + j] * s_dv[c];
        __syncthreads();
    }
    int gj = layer*128 + j;
    float h2 = AGG[v*128 + j] + acc*dinv[v];
    h2 = fmaxf(h2, 0.0f);
    float scale = bng[gj] / sqrtf(bnv[gj] + 1e-5f);
    h2 = (h2 - bnm[gj])*scale + bnb[gj];
    float a = prelua[0];
    h2 = (h2 > 0.0f) ? h2 : a*h2;
    AGG[v*128 + j] = h2;
    red[j] = h2 * poolp[gj]; __syncthreads();
    for (int st = 64; st > 0; st >>= 1) { if (j < st) red[j] += red[j+st]; __syncthreads(); }
    if (j == 0) {
        float sc = tanhf(red[0] / pnorm[layer]);
        score[v] = sc;
        keys[v]  = orderKey(sc);
    }
}

// ---------------------------------------------------------------- fused top-k, all phases grid-parallel
__global__ __launch_bounds__(1024) void k_topk(const unsigned* __restrict__ keys,
                                               int* __restrict__ gh, int* __restrict__ selbuf,
                                               int* __restrict__ degN,
                                               int* __restrict__ remap, int* __restrict__ keep_ids,
                                               int* __restrict__ bar, int n, int kk) {
    __shared__ int lh[2048];
    __shared__ int s_d1, s_r1, s_c1, s_dA, s_rA, s_cA, s_dB, s_ntk, s_cnt3, s_bC, s_r2, s_lowD, s_lowR;
    __shared__ int s_base, s_cur;
    int t = threadIdx.x, b = blockIdx.x, lane = t & 63;
    int* h1 = gh;
    int* h2 = gh + 2048;
    int* h3 = gh + 4096;
    int* h4 = gh + 5120;
    int* h5 = gh + 5376;

    for (int i = b*1024 + t; i < NMAX; i += TKB*1024) degN[i] = 0;

    int nR = (n + 1023) & ~1023;
    lh[t] = 0; lh[t+1024] = 0;
    __syncthreads();
    for (int i = b*1024 + t; i < nR; i += TKB*1024) {
        bool act = (i < n);
        int bin = act ? (int)(keys[i] >> 21) : 0;
        histAdd(lh, bin, act, 11);
    }
    __syncthreads();
    { int c = lh[t]; if (c) atomicAdd(&h1[t], c); c = lh[t+1024]; if (c) atomicAdd(&h1[t+1024], c); }
    gridbar(&bar[0], TKB);
    selScan2048(h1, kk, &s_d1, &s_r1, &s_c1);
    int bstar = s_d1;

    lh[t] = 0; lh[t+1024] = 0;
    __syncthreads();
    for (int i = b*1024 + t; i < nR; i += TKB*1024) {
        bool act = false; int bin = 0;
        if (i < n) { unsigned key = keys[i]; act = ((int)(key >> 21) == bstar); bin = (int)((key >> 10) & 2047); }
        histAdd(lh, act ? bin : 0, act, 11);
    }
    __syncthreads();
    { int c = lh[t]; if (c) atomicAdd(&h2[t], c); c = lh[t+1024]; if (c) atomicAdd(&h2[t+1024], c); }
    gridbar(&bar[1], TKB);
    selScan2048(h2, s_r1, &s_dA, &s_rA, &s_cA);
    unsigned top21 = ((unsigned)bstar << 11) | (unsigned)s_dA;

    lh[t] = 0;
    __syncthreads();
    for (int i = b*1024 + t; i < nR; i += TKB*1024) {
        bool act = false; int bin = 0;
        if (i < n) { unsigned key = keys[i]; act = ((key >> 10) == top21); bin = (int)(key & 1023); }
        histAdd(lh, act ? bin : 0, act, 10);
    }
    __syncthreads();
    { int c = lh[t]; if (c) atomicAdd(&h3[t], c); }
    gridbar(&bar[2], TKB);
    selScan1024(h3, s_rA, &s_dB, &s_ntk, &s_cnt3);
    unsigned thresh = (top21 << 10) | (unsigned)s_dB;

    int cut;
    if (s_cnt3 == s_ntk) {
        // no boundary tie ambiguity: keep every key == thresh (common case for continuous scores)
        cut = n - 1;
    } else {
        if (t < 256) lh[t] = 0;
        __syncthreads();
        for (int i = b*1024 + t; i < n; i += TKB*1024)
            if (keys[i] == thresh) atomicAdd(&lh[i >> 8], 1);
        __syncthreads();
        if (t < 256) { int c = lh[t]; if (c) atomicAdd(&h4[t], c); }
        gridbar(&bar[3], TKB);
        prefixSel256(lh, h4, s_ntk, &s_bC, &s_r2);
        int bC = s_bC;

        if (t < 256) lh[t] = 0;
        __syncthreads();
        for (int i = b*1024 + t; i < n; i += TKB*1024)
            if (keys[i] == thresh && (i >> 8) == bC) atomicAdd(&lh[i & 255], 1);
        __syncthreads();
        if (t < 256) { int c = lh[t]; if (c) atomicAdd(&h5[t], c); }
        gridbar(&bar[4], TKB);
        prefixSel256(lh, h5, s_r2, &s_lowD, &s_lowR);
        cut = (bC << 8) | s_lowD;
    }

    {
        int cnt = 0;
        for (int base = b*1024; base < n; base += TKB*1024) {
            int i = base + t;
            if (i < n) {
                unsigned key = keys[i];
                cnt += (key > thresh) || (key == thresh && i <= cut);
            }
        }
        lh[t] = cnt; __syncthreads();
        for (int st = 512; st > 0; st >>= 1) { if (t < st) lh[t] += lh[t+st]; __syncthreads(); }
        if (t == 0) { s_base = atomicAdd(&selbuf[5], lh[0]); s_cur = 0; }
        __syncthreads();
        for (int base = b*1024; base < n; base += TKB*1024) {
            int i = base + t;
            bool keep = false;
            if (i < n) {
                unsigned key = keys[i];
                keep = (key > thresh) || (key == thresh && i <= cut);
            }
            unsigned long long m = __ballot(keep);
            int wcnt = __popcll(m);
            int wbase = 0;
            if (lane == 0 && wcnt) wbase = atomicAdd(&s_cur, wcnt);
            wbase = __shfl(wbase, 0);
            if (keep) {
                int slot = s_base + wbase + __popcll(m & ((1ULL << lane) - 1));
                remap[i] = slot; keep_ids[slot] = i;
            } else if (i < n) remap[i] = -1;
        }
    }
}

// ---------------------------------------------------------------- fused pool stats + next-layer GEMM + edge compact
// blocks [0,gb): stage pooled rows into LDS (stats fold free, transposed scr write) + gemm for layer i+1
//   with 4-deep rotating-register prefetch of W/V columns (hide L2 latency under FMAs)
// blocks [gb,gb+EBLK): edge remap/compact (+next-layer degree/rank)
__global__ __launch_bounds__(128) void k_poolgemm(
        const float* __restrict__ AGGc, const float* __restrict__ score,
        const int* __restrict__ keep_ids, const int* __restrict__ remap,
        float* __restrict__ scr,
        const int* __restrict__ esrcP, const int* __restrict__ edstP,
        int* __restrict__ esrcN, int* __restrict__ edstN, int* __restrict__ erankN,
        const int* __restrict__ ecntP, int* __restrict__ ecntN, int* __restrict__ degN,
        const float* __restrict__ W, const float* __restrict__ V, const float* __restrict__ bias,
        float* __restrict__ HW, float* __restrict__ AGGn, int k, int gb, int do_gemm) {
    int b = blockIdx.x, t = threadIdx.x;
    __shared__ __align__(16) float ht[128*HTS];   // 10.2 KB -> ~15 blocks/CU
    if (b < gb) {
        int v0 = b * GRB;
        float mx = -3.402823e38f, sm = 0.f;
        #pragma unroll
        for (int it = 0; it < GRB; it++) {
            int r = v0 + it;
            bool valid = (r < k);
            int vv = keep_ids[valid ? r : (k - 1)];
            float val = AGGc[(size_t)vv*128 + t] * score[vv];
            if (!valid) val = 0.f;
            ht[t*HTS + it] = val;
            if (valid) { mx = fmaxf(mx, val); sm += val; }
        }
        scr[(size_t)t*GBMAX + b]       = mx;   // transposed: channel-major rows
        scr[(size_t)(t+128)*GBMAX + b] = sm;
        if (!do_gemm) return;
        __syncthreads();
        float accW[GRB], accV[GRB];
        #pragma unroll
        for (int r = 0; r < GRB; r++) { accW[r] = 0.0f; accV[r] = 0.0f; }
        const float* Wp = W + t;
        const float* Vp = V + t;
        float w0 = Wp[0],   w1 = Wp[128],   w2 = Wp[256],   w3 = Wp[384];
        float y0 = Vp[0],   y1 = Vp[128],   y2 = Vp[256],   y3 = Vp[384];
        for (int kk = 0; kk < 128; kk += 4) {
            int nk = (kk + 4) & 127;                       // wraps at end: harmless L1-hot loads
            float nw0 = Wp[nk*128],       nw1 = Wp[nk*128 + 128];
            float nw2 = Wp[nk*128 + 256], nw3 = Wp[nk*128 + 384];
            float ny0 = Vp[nk*128],       ny1 = Vp[nk*128 + 128];
            float ny2 = Vp[nk*128 + 256], ny3 = Vp[nk*128 + 384];
            {
                const float* hp = &ht[kk*HTS];
                #pragma unroll
                for (int r4 = 0; r4 < GRB; r4 += 4) {
                    float4 hq = *(const float4*)(hp + r4);
                    accW[r4+0] += hq.x*w0;  accV[r4+0] += hq.x*y0;
                    accW[r4+1] += hq.y*w0;  accV[r4+1] += hq.y*y0;
                    accW[r4+2] += hq.z*w0;  accV[r4+2] += hq.z*y0;
                    accW[r4+3] += hq.w*w0;  accV[r4+3] += hq.w*y0;
                }
            }
            {
                const float* hp = &ht[(kk+1)*HTS];
                #pragma unroll
                for (int r4 = 0; r4 < GRB; r4 += 4) {
                    float4 hq = *(const float4*)(hp + r4);
                    accW[r4+0] += hq.x*w1;  accV[r4+0] += hq.x*y1;
                    accW[r4+1] += hq.y*w1;  accV[r4+1] += hq.y*y1;
                    accW[r4+2] += hq.z*w1;  accV[r4+2] += hq.z*y1;
                    accW[r4+3] += hq.w*w1;  accV[r4+3] += hq.w*y1;
                }
            }
            {
                const float* hp = &ht[(kk+2)*HTS];
                #pragma unroll
                for (int r4 = 0; r4 < GRB; r4 += 4) {
                    float4 hq = *(const float4*)(hp + r4);
                    accW[r4+0] += hq.x*w2;  accV[r4+0] += hq.x*y2;
                    accW[r4+1] += hq.y*w2;  accV[r4+1] += hq.y*y2;
                    accW[r4+2] += hq.z*w2;  accV[r4+2] += hq.z*y2;
                    accW[r4+3] += hq.w*w2;  accV[r4+3] += hq.w*y2;
                }
            }
            {
                const float* hp = &ht[(kk+3)*HTS];
                #pragma unroll
                for (int r4 = 0; r4 < GRB; r4 += 4) {
                    float4 hq = *(const float4*)(hp + r4);
                    accW[r4+0] += hq.x*w3;  accV[r4+0] += hq.x*y3;
                    accW[r4+1] += hq.y*w3;  accV[r4+1] += hq.y*y3;
                    accW[r4+2] += hq.z*w3;  accV[r4+2] += hq.z*y3;
                    accW[r4+3] += hq.w*w3;  accV[r4+3] += hq.w*y3;
                }
            }
            w0 = nw0; w1 = nw1; w2 = nw2; w3 = nw3;
            y0 = ny0; y1 = ny1; y2 = ny2; y3 = ny3;
        }
        float bb = bias[t];
        #pragma unroll
        for (int r = 0; r < GRB; r++) {
            int v = v0 + r;
            if (v >= k) break;
            HW[(size_t)v*128 + t]   = accW[r];
            AGGn[(size_t)v*128 + t] = accV[r] + bb;
        }
    } else {
        int eb = b - gb, lane = t & 63;
        int ec = *ecntP;
        int* red = (int*)ht;
        __shared__ int s_base, s_cur;
        int cnt = 0;
        for (int base = eb*128; base < ec; base += EBLK*128) {
            int e = base + t;
            if (e < ec) {
                int ns = remap[esrcP[e]], nd = remap[edstP[e]];
                cnt += (ns >= 0 && nd >= 0);
            }
        }
        red[t] = cnt; __syncthreads();
        for (int st = 64; st > 0; st >>= 1) { if (t < st) red[t] += red[t+st]; __syncthreads(); }
        if (t == 0) { s_base = atomicAdd(ecntN, red[0]); s_cur = 0; }
        __syncthreads();
        for (int base = eb*128; base < ec; base += EBLK*128) {
            int e = base + t;
            bool keep = false; int ns = 0, nd = 0;
            if (e < ec) {
                ns = remap[esrcP[e]]; nd = remap[edstP[e]];
                keep = (ns >= 0 && nd >= 0);
            }
            unsigned long long m = __ballot(keep);
            int wcnt = __popcll(m);
            int wbase = 0;
            if (lane == 0 && wcnt) wbase = atomicAdd(&s_cur, wcnt);
            wbase = __shfl(wbase, 0);
            if (keep) {
                int pos = s_base + wbase + __popcll(m & ((1ULL << lane) - 1));
                esrcN[pos] = ns; edstN[pos] = nd;
                erankN[pos] = atomicAdd(&degN[nd], 1);
            }
        }
    }
}

// ---------------------------------------------------------------- final-layer scratch reduce (parallel, 1 channel/block)
__global__ __launch_bounds__(256) void k_pred(const float* __restrict__ scr, float* __restrict__ rbuf,
                                              int gbP, int L) {
    poolReduceT(scr, rbuf, gbP, L, blockIdx.x);
}

// ---------------------------------------------------------------- MLP head
__global__ __launch_bounds__(320) void k_lin1(const float* __restrict__ rbuf,
                                              const float* __restrict__ w1,
                                              float* __restrict__ z1part) {
    int b = blockIdx.x, t = threadIdx.x;
    int j = t*4;
    float4 acc = make_float4(0.f, 0.f, 0.f, 0.f);
    int i0 = b*40;
    for (int r = 0; r < 40; r++) {
        int i = i0 + r;
        float rv = rbuf[i];
        if (i & 128) rv *= c_invk[i >> 8];
        float4 w = *(const float4*)(w1 + (size_t)i*1280 + j);
        acc.x += rv*w.x; acc.y += rv*w.y; acc.z += rv*w.z; acc.w += rv*w.w;
    }
    *(float4*)(z1part + b*1280 + j) = acc;
}

__global__ __launch_bounds__(320) void k_lin2(const float* __restrict__ z1part,
                                              const float* __restrict__ b1,
                                              const float* __restrict__ w2, const float* __restrict__ b2,
                                              const float* __restrict__ prelua, float* __restrict__ out) {
    int t = threadIdx.x, lane = t & 63, wid = t >> 6;
    float a = prelua[0];
    int j = t*4;
    float4 acc = make_float4(0.f, 0.f, 0.f, 0.f);
    for (int p = 0; p < LIN1B; p++) {
        float4 v = *(const float4*)(z1part + p*1280 + j);
        acc.x += v.x; acc.y += v.y; acc.z += v.z; acc.w += v.w;
    }
    float4 bb = *(const float4*)(b1 + j);
    float z0 = acc.x + bb.x; z0 = z0 > 0.f ? z0 : a*z0;
    float z1 = acc.y + bb.y; z1 = z1 > 0.f ? z1 : a*z1;
    float z2 = acc.z + bb.z; z2 = z2 > 0.f ? z2 : a*z2;
    float z3 = acc.w + bb.w; z3 = z3 > 0.f ? z3 : a*z3;
    float s[8];
    #pragma unroll
    for (int o = 0; o < 8; o++)
        s[o] = z0*w2[(j+0)*8+o] + z1*w2[(j+1)*8+o] + z2*w2[(j+2)*8+o] + z3*w2[(j+3)*8+o];
    #pragma unroll
    for (int off = 32; off > 0; off >>= 1)
        #pragma unroll
        for (int o = 0; o < 8; o++) s[o] += __shfl_down(s[o], off);
    __shared__ float sred[5][8];
    if (lane == 0)
        for (int o = 0; o < 8; o++) sred[wid][o] = s[o];
    __syncthreads();
    if (t == 0) {
        float zo[8];
        for (int o = 0; o < 8; o++) {
            float z = sred[0][o]+sred[1][o]+sred[2][o]+sred[3][o]+sred[4][o] + b2[o];
            zo[o] = z > 0.f ? z : a*z;
        }
        float mn = zo[0];
        for (int o = 1; o < 8; o++) mn = fminf(mn, zo[o]);
        float v[8], mx = -3.402823e38f;
        for (int o = 0; o < 8; o++) { v[o] = zo[o] - mn; mx = fmaxf(mx, v[o]); }
        float sm = 0.f;
        for (int o = 0; o < 8; o++) { v[o] = v[o] / mx; sm += v[o]; }
        for (int o = 0; o < 8; o++) out[o] = v[o] / sm;
    }
}

// ---------------------------------------------------------------- launch
extern "C" void kernel_launch(void* const* d_in, const int* in_sizes, int n_in,
                              void* d_out, int out_size, void* d_ws, size_t ws_size,
                              hipStream_t stream) {
    const float* x      = (const float*)d_in[0];
    const int*   eidx   = (const int*)  d_in[1];
    const float* W1     = (const float*)d_in[2];
    const float* V1     = (const float*)d_in[3];
    const float* Ws     = (const float*)d_in[4];
    const float* Vs     = (const float*)d_in[5];
    const float* convb  = (const float*)d_in[6];
    const float* bng    = (const float*)d_in[7];
    const float* bnb    = (const float*)d_in[8];
    const float* bnm    = (const float*)d_in[9];
    const float* bnv    = (const float*)d_in[10];
    const float* poolp  = (const float*)d_in[11];
    const float* prelua = (const float*)d_in[12];
    const float* w1     = (const float*)d_in[13];
    const float* b1     = (const float*)d_in[14];
    const float* w2     = (const float*)d_in[15];
    const float* b2     = (const float*)d_in[16];
    float* out = (float*)d_out;

    float* wsf  = (float*)d_ws;
    float* aggA   = wsf;                          // NMAX*128
    float* aggB   = aggA  + (size_t)NMAX*128;
    float* HW     = aggB  + (size_t)NMAX*128;
    float* dinv   = HW    + (size_t)NMAX*128;
    float* score  = dinv  + NMAX;
    float* rbuf   = score + NMAX;
    float* pnorm  = rbuf  + 2560;
    float* z1part = pnorm + 16;                   // LIN1B*1280
    float* scr    = z1part + LIN1B*1280;          // 256*GBMAX (transposed: [ch][block])
    unsigned* keys = (unsigned*)(scr + (size_t)GBMAX*256);
    int* esrcA  = (int*)(keys + NMAX);
    int* edstA  = esrcA + NEDGE;
    int* erankA = edstA + NEDGE;
    int* esrcB  = erankA + NEDGE;
    int* edstB  = esrcB + NEDGE;
    int* erankB = edstB + NEDGE;
    int* csr    = erankB + NEDGE;
    int* degA   = csr   + NEDGE;
    int* degB   = degA  + NMAX;
    int* ghist  = degB  + NMAX;                   // GHN
    int* offs   = ghist + GHN;
    int* remap  = offs  + NMAX;
    int* keep_ids = remap + NMAX;
    int* lbsum  = keep_ids + NMAX;                // SB*2
    int* ecnt   = lbsum + SB*2;                   // 16
    int* selbuf = ecnt  + 16;                     // 16
    int* tkc    = selbuf + 16;                    // 64

    static const int NS[10] = {40000,32000,25600,20480,16384,13108,10487,8390,6712,5370};
    static const int KS[10] = {32000,25600,20480,16384,13108,10487,8390,6712,5370,4296};

    hipMemsetAsync(degA, 0, (size_t)NMAX*sizeof(int), stream);
    k_init<<<2500, 256, 0, stream>>>(eidx, esrcA, edstA, erankA, poolp, rbuf, pnorm,
                                     ecnt, degA, tkc);

    for (int i = 0; i < 10; i++) {
        int n = NS[i], k = KS[i];
        int chunk = (n + SB - 1) / SB;
        int* esrcP  = (i & 1) ? esrcB  : esrcA;
        int* edstP  = (i & 1) ? edstB  : edstA;
        int* erankP = (i & 1) ? erankB : erankA;
        int* esrcN  = (i & 1) ? esrcA  : esrcB;
        int* edstN  = (i & 1) ? edstA  : edstB;
        int* erankN = (i & 1) ? erankA : erankB;
        int* degP   = (i & 1) ? degB : degA;
        int* degN   = (i & 1) ? degA : degB;
        float* AGGc = (i & 1) ? aggB : aggA;      // current layer features
        float* AGGn = (i & 1) ? aggA : aggB;      // next layer buffer

        int gbP = (i == 0) ? 0 : (KS[i-1] + GRB - 1) / GRB;
        k_presum<<<SB, 256, 0, stream>>>(degP, lbsum, n, chunk);
        k_scan<<<SB + PRB, 256, 0, stream>>>(degP, offs, dinv, ghist, selbuf,
                                             lbsum, scr, rbuf, n, chunk,
                                             gbP, i - 1);

        k_fill<<<FB, 128, 0, stream>>>(esrcP, edstP, erankP, offs, csr, &ecnt[i]);

        if (i == 0) {
            k_gather0<<<n, 128, 0, stream>>>(x, W1, V1, convb,
                                             bng, bnb, bnm, bnv, poolp, pnorm, prelua,
                                             offs, degP, dinv, csr, AGGc, score, keys);
        } else {
            k_gather<<<n, 128, 0, stream>>>(HW, AGGc, offs, degP, dinv, csr,
                                            bng, bnb, bnm, bnv, poolp, pnorm, prelua,
                                            score, keys, i);
        }

        k_topk<<<TKB, 1024, 0, stream>>>(keys, ghist, selbuf, degN,
                                         remap, keep_ids, tkc + i*5, n, k);

        int gb = (k + GRB - 1) / GRB;
        int do_gemm = (i < 9);
        int grid = gb + (do_gemm ? EBLK : 0);
        // gemm computes layer i+1: weights Ws[(i+1)-1] = Ws + i*16384, bias convb+(i+1)*128
        k_poolgemm<<<grid, 128, 0, stream>>>(AGGc, score, keep_ids, remap, scr,
                                             esrcP, edstP, esrcN, edstN, erankN,
                                             &ecnt[i], &ecnt[i+1], degN,
                                             Ws + (size_t)min(i,8)*16384,
                                             Vs + (size_t)min(i,8)*16384,
                                             convb + min(i+1,9)*128,
                                             HW, AGGn, k, gb, do_gemm);
    }

    k_pred<<<PRB, 256, 0, stream>>>(scr, rbuf, (KS[9] + GRB - 1) / GRB, 9);
    k_lin1<<<LIN1B, 320, 0, stream>>>(rbuf, w1, z1part);
    k_lin2<<<1, 320, 0, stream>>>(z1part, b1, w2, b2, prelua, out);
}

// Round 7
// 978.720 us; speedup vs baseline: 1.1189x; 1.1189x over previous
//
#include <hip/hip_runtime.h>
#include <hip/hip_bf16.h>

#define NEDGE 640000
#define NMAX  40000
#define SB    40      // scan blocks
#define PRB   256     // parallel pool-reduce blocks (1 channel each)
#define EBLK  512     // edge-compact blocks (128 thr)
#define FB    1280    // fill blocks (128 thr each)
#define LIN1B 64      // lin1 partial blocks
#define GRB   16      // gemm rows per block (r2-best shape: 128 thr, 10.2 KB LDS, ~15 blocks/CU)
#define HTS   20      // ht row stride (GRB+4, multiple of 4 for float4 reads)
#define TKB   32      // fused top-k blocks
#define GHN   5632    // global hist ints (2048+2048+1024+256+256)
#define GBMAX 2048    // scr rows (>= max gemm blocks per layer = 2000)

// ---------------------------------------------------------------- helpers
__device__ inline unsigned orderKey(float s) {
    unsigned b = __float_as_uint(s);
    return (b & 0x80000000u) ? ~b : (b | 0x80000000u);
}

// ballot-dedup LDS histogram insert: O(1) atomics per distinct bin per wave
__device__ inline void histAdd(int* sh, int bin, bool act, int nbits) {
    unsigned long long mm = __ballot(act);
    for (int b = 0; b < nbits; b++) {
        unsigned long long bal = __ballot(act && ((bin >> b) & 1));
        mm &= ((bin >> b) & 1) ? bal : ~bal;
    }
    if (act) {
        int lane = threadIdx.x & 63;
        int leader = __ffsll(mm) - 1;
        if (lane == leader) atomicAdd(&sh[bin], __popcll(mm));
    }
}

// grid barrier for co-resident blocks (fresh counter per use, zeroed in k_init)
__device__ inline void gridbar(int* ctr, int target) {
    __syncthreads();
    if (threadIdx.x == 0) {
        __threadfence();
        __hip_atomic_fetch_add(ctr, 1, __ATOMIC_RELEASE, __HIP_MEMORY_SCOPE_AGENT);
        while (__hip_atomic_load(ctr, __ATOMIC_ACQUIRE, __HIP_MEMORY_SCOPE_AGENT) < target)
            __builtin_amdgcn_s_sleep(1);
        __threadfence();
    }
    __syncthreads();
}

__device__ inline int waveScanIncl(int v) {
    int lane = threadIdx.x & 63;
    #pragma unroll
    for (int off = 1; off < 64; off <<= 1) {
        int o = __shfl_up(v, off);
        if (lane >= off) v += o;
    }
    return v;
}

// find bin d such that suffix-sum S[d] >= rem > S[d+1] over 2048 bins, via shfl prefix scan.
// outR = rem - S[d+1]; outCnt = h[d]. 1024 threads, 2 bins/thread.
__device__ inline void selScan2048(const int* gh, int rem, int* outD, int* outR, int* outCnt) {
    __shared__ int wtot[16];
    __shared__ int s_T;
    int t = threadIdx.x, lane = t & 63, wid = t >> 6;
    int a0 = gh[2*t], a1 = gh[2*t+1];
    int s  = a0 + a1;
    int ws = waveScanIncl(s);
    if (lane == 63) wtot[wid] = ws;
    __syncthreads();
    if (t < 16) {
        int v = wtot[t];
        #pragma unroll
        for (int off = 1; off < 16; off <<= 1) { int o = __shfl_up(v, off); if (lane >= off) v += o; }
        wtot[t] = v;
        if (t == 15) s_T = v;
    }
    __syncthreads();
    int base = (wid > 0) ? wtot[wid-1] : 0;
    int inclPair = base + ws;          // inclusive prefix through bin 2t+1
    int P1 = inclPair - a1;            // exclusive prefix of bin 2t+1
    int P0 = P1 - a0;                  // exclusive prefix of bin 2t
    int Q = s_T - rem;
    if (a0 > 0 && P0 <= Q && Q < P0 + a0) { *outD = 2*t;   *outR = a0 - (Q - P0); *outCnt = a0; }
    if (a1 > 0 && P1 <= Q && Q < P1 + a1) { *outD = 2*t+1; *outR = a1 - (Q - P1); *outCnt = a1; }
    __syncthreads();
}

// same over 1024 bins, 1 bin/thread
__device__ inline void selScan1024(const int* gh, int rem, int* outD, int* outR, int* outCnt) {
    __shared__ int wtot[16];
    __shared__ int s_T;
    int t = threadIdx.x, lane = t & 63, wid = t >> 6;
    int a0 = gh[t];
    int ws = waveScanIncl(a0);
    if (lane == 63) wtot[wid] = ws;
    __syncthreads();
    if (t < 16) {
        int v = wtot[t];
        #pragma unroll
        for (int off = 1; off < 16; off <<= 1) { int o = __shfl_up(v, off); if (lane >= off) v += o; }
        wtot[t] = v;
        if (t == 15) s_T = v;
    }
    __syncthreads();
    int base = (wid > 0) ? wtot[wid-1] : 0;
    int P0 = base + ws - a0;           // exclusive prefix
    int Q = s_T - rem;
    if (a0 > 0 && P0 <= Q && Q < P0 + a0) { *outD = t; *outR = a0 - (Q - P0); *outCnt = a0; }
    __syncthreads();
}

__device__ inline void prefixSel256(int* lh, const int* gh, int rem, int* outD, int* outR) {
    int t = threadIdx.x;
    if (t < 256) lh[t] = gh[t];
    __syncthreads();
    for (int off = 1; off < 256; off <<= 1) {
        int v = 0;
        if (t < 256) v = lh[t] + ((t >= off) ? lh[t-off] : 0);
        __syncthreads();
        if (t < 256) lh[t] = v;
        __syncthreads();
    }
    if (t < 256) {
        int P = lh[t], Pp = (t == 0) ? 0 : lh[t-1];
        if (P >= rem && Pp < rem) { *outD = t; *outR = rem - Pp; }
    }
    __syncthreads();
}

// parallel pool-stat reduce over COALESCED scr layout [block][256ch]:
// one block per channel ch; threads stride the gemm-block axis r at scr[r*256+ch].
// ≤8 iters/thread, lines L2-shared across neighboring-channel blocks.
__device__ inline void poolReduceC(const float* __restrict__ scr, float* __restrict__ rbuf,
                                   int gbP, int L, int ch) {
    int t = threadIdx.x;
    bool isMax = ch < 128;
    float acc = isMax ? -3.402823e38f : 0.f;
    for (int r = t; r < gbP; r += 256) {
        float v = scr[(size_t)r*256 + ch];
        acc = isMax ? fmaxf(acc, v) : (acc + v);
    }
    __shared__ float red[256];
    red[t] = acc; __syncthreads();
    for (int st = 128; st > 0; st >>= 1) {
        if (t < st) red[t] = isMax ? fmaxf(red[t], red[t+st]) : (red[t] + red[t+st]);
        __syncthreads();
    }
    if (t == 0) rbuf[L*256 + ch] = red[0];
}

__device__ const float c_invk[10] = {
    1.0f/32000.0f, 1.0f/25600.0f, 1.0f/20480.0f, 1.0f/16384.0f, 1.0f/13108.0f,
    1.0f/10487.0f, 1.0f/8390.0f,  1.0f/6712.0f,  1.0f/5370.0f,  1.0f/4296.0f };

// ---------------------------------------------------------------- init (+ layer-0 degree count + ranks)
__global__ void k_init(const int* __restrict__ eidx, int* __restrict__ esrc,
                       int* __restrict__ edst, int* __restrict__ erank,
                       const float* __restrict__ poolp,
                       float* __restrict__ rbuf, float* __restrict__ pnorm,
                       int* __restrict__ ecnt, int* __restrict__ degA,
                       int* __restrict__ tkc) {
    int b = blockIdx.x, t = threadIdx.x;
    if (b < 10) {
        rbuf[b*256 + t] = (t < 128) ? -3.402823e38f : 0.0f;
        __shared__ float red[256];
        float v = 0.0f;
        if (t < 128) { float pv = poolp[b*128 + t]; v = pv*pv; }
        red[t] = v; __syncthreads();
        for (int s = 128; s > 0; s >>= 1) { if (t < s) red[t] += red[t+s]; __syncthreads(); }
        if (t == 0) pnorm[b] = sqrtf(red[0]);
    }
    if (b == 10 && t < 16) ecnt[t] = (t == 0) ? NEDGE : 0;
    if (b == 11 && t < 64) tkc[t] = 0;
    int e = b*256 + t;
    if (e < NEDGE) {
        int d = eidx[NEDGE + e];
        esrc[e] = eidx[e]; edst[e] = d;
        erank[e] = atomicAdd(&degA[d], 1);
    }
}

// ---------------------------------------------------------------- per-chunk sums (kernel-boundary replaces barrier)
__global__ __launch_bounds__(256) void k_presum(const int* __restrict__ deg,
                                                int* __restrict__ lbsum,
                                                int n, int chunk) {
    int b = blockIdx.x, t = threadIdx.x;
    __shared__ int red[256];
    int start = b*chunk, end = min(start + chunk, n);
    int s = 0;
    for (int i = start + t; i < end; i += 256) s += deg[i];
    red[t] = s; __syncthreads();
    for (int st = 128; st > 0; st >>= 1) { if (t < st) red[t] += red[t+st]; __syncthreads(); }
    if (t == 0) lbsum[b] = red[0];
}

// ---------------------------------------------------------------- scan + parallel pool reduce
// blocks [0,SB): scan; blocks [SB,SB+PRB): reduce previous layer's pool scratch (1 channel each)
__global__ void k_scan(const int* __restrict__ deg,
                       int* __restrict__ offs, float* __restrict__ dinv,
                       int* __restrict__ ghist, int* __restrict__ selbuf,
                       const int* __restrict__ lbsum,
                       const float* __restrict__ scr, float* __restrict__ rbuf,
                       int n, int chunk, int gbP, int prevL) {
    int b = blockIdx.x, t = threadIdx.x, lane = t & 63, wid = t >> 6;
    if (b >= SB) {
        if (gbP > 0) poolReduceC(scr, rbuf, gbP, prevL, b - SB);
        return;
    }
    __shared__ int s_excl;
    __shared__ int wsum[4];
    __shared__ int s_carry;
    __shared__ int s_sums[SB];
    if (b == 0) {
        for (int jj = t; jj < GHN; jj += 256) ghist[jj] = 0;
        if (t == 0) { selbuf[2] = 0; selbuf[5] = 0; }
    }
    if (t < SB) s_sums[t] = lbsum[t];
    __syncthreads();
    if (t == 0) {
        int excl = 0;
        for (int p = 0; p < b; p++) excl += s_sums[p];
        s_excl = excl;
    }
    __syncthreads();
    if (t == 0) s_carry = s_excl;
    __syncthreads();
    int start = b*chunk, end = min(start + chunk, n);
    for (int base = start; base < end; base += 256) {
        int i = base + t;
        int d = (i < end) ? deg[i] : 0;
        int incl = d;
        for (int off = 1; off < 64; off <<= 1) {
            int o = __shfl_up(incl, off);
            if (lane >= off) incl += o;
        }
        if (lane == 63) wsum[wid] = incl;
        __syncthreads();
        if (t == 0) { int c = s_carry; for (int w = 0; w < 4; w++) { int tmp = wsum[w]; wsum[w] = c; c += tmp; } s_carry = c; }
        __syncthreads();
        int p = wsum[wid] + incl - d;
        if (i < end) {
            offs[i] = p;
            dinv[i] = (d > 0) ? 1.0f/sqrtf((float)d) : 0.0f;
        }
        __syncthreads();
    }
}

// ---------------------------------------------------------------- slim CSR fill (rank-based, no atomics, no LDS)
__global__ __launch_bounds__(128) void k_fill(const int* __restrict__ esrc, const int* __restrict__ edst,
                                              const int* __restrict__ erank, const int* __restrict__ offs,
                                              int* __restrict__ csr, const int* __restrict__ ecnt) {
    int ec = *ecnt;
    for (int e = blockIdx.x*128 + threadIdx.x; e < ec; e += FB*128)
        csr[offs[edst[e]] + erank[e]] = esrc[e];
}

// ---------------------------------------------------------------- layer-0 fused node update
__global__ __launch_bounds__(128) void k_gather0(
    const float* __restrict__ x, const float* __restrict__ W1, const float* __restrict__ V1,
    const float* __restrict__ convb,
    const float* __restrict__ bng, const float* __restrict__ bnb,
    const float* __restrict__ bnm, const float* __restrict__ bnv,
    const float* __restrict__ poolp, const float* __restrict__ pnorm,
    const float* __restrict__ prelua,
    const int* __restrict__ offs, const int* __restrict__ deg, const float* __restrict__ dinv,
    const int* __restrict__ csr,
    float* __restrict__ AGG, float* __restrict__ score, unsigned* __restrict__ keys) {
    int v = blockIdx.x, j = threadIdx.x;
    __shared__ float red[128];
    int off = offs[v], dg = deg[v];
    float accs = 0.0f;
    for (int c = j; c < dg; c += 128) { int s = csr[off + c]; accs += x[s]*dinv[s]; }
    red[j] = accs; __syncthreads();
    for (int st = 64; st > 0; st >>= 1) { if (j < st) red[j] += red[j+st]; __syncthreads(); }
    float aggs = red[0] * dinv[v];
    __syncthreads();
    float h2 = aggs*W1[j] + x[v]*V1[j] + convb[j];
    h2 = fmaxf(h2, 0.0f);
    float scale = bng[j] / sqrtf(bnv[j] + 1e-5f);
    h2 = (h2 - bnm[j])*scale + bnb[j];
    float a = prelua[0];
    h2 = (h2 > 0.0f) ? h2 : a*h2;
    AGG[v*128 + j] = h2;
    red[j] = h2 * poolp[j]; __syncthreads();
    for (int st = 64; st > 0; st >>= 1) { if (j < st) red[j] += red[j+st]; __syncthreads(); }
    if (j == 0) {
        float sc = tanhf(red[0] / pnorm[0]);
        score[v] = sc;
        keys[v]  = orderKey(sc);
    }
}

// ---------------------------------------------------------------- generic fused gather + update + score
__global__ __launch_bounds__(128) void k_gather(
    const float* __restrict__ HW, float* __restrict__ AGG,
    const int* __restrict__ offs, const int* __restrict__ deg, const float* __restrict__ dinv,
    const int* __restrict__ csr,
    const float* __restrict__ bng, const float* __restrict__ bnb,
    const float* __restrict__ bnm, const float* __restrict__ bnv,
    const float* __restrict__ poolp, const float* __restrict__ pnorm,
    const float* __restrict__ prelua,
    float* __restrict__ score, unsigned* __restrict__ keys, int layer) {
    int v = blockIdx.x, j = threadIdx.x;
    __shared__ int   s_src[128];
    __shared__ float s_dv[128];
    __shared__ float red[128];
    int off = offs[v], dg = deg[v];
    float acc = 0.0f;
    for (int base = 0; base < dg; base += 128) {
        int cnt = min(128, dg - base);
        if (j < cnt) { int s = csr[off + base + j]; s_src[j] = s; s_dv[j] = dinv[s]; }
        __syncthreads();
        for (int c = 0; c < cnt; c++) acc += HW[s_src[c]*128 + j] * s_dv[c];
        __syncthreads();
    }
    int gj = layer*128 + j;
    float h2 = AGG[v*128 + j] + acc*dinv[v];
    h2 = fmaxf(h2, 0.0f);
    float scale = bng[gj] / sqrtf(bnv[gj] + 1e-5f);
    h2 = (h2 - bnm[gj])*scale + bnb[gj];
    float a = prelua[0];
    h2 = (h2 > 0.0f) ? h2 : a*h2;
    AGG[v*128 + j] = h2;
    red[j] = h2 * poolp[gj]; __syncthreads();
    for (int st = 64; st > 0; st >>= 1) { if (j < st) red[j] += red[j+st]; __syncthreads(); }
    if (j == 0) {
        float sc = tanhf(red[0] / pnorm[layer]);
        score[v] = sc;
        keys[v]  = orderKey(sc);
    }
}

// ---------------------------------------------------------------- fused top-k, all phases grid-parallel
__global__ __launch_bounds__(1024) void k_topk(const unsigned* __restrict__ keys,
                                               int* __restrict__ gh, int* __restrict__ selbuf,
                                               int* __restrict__ degN,
                                               int* __restrict__ remap, int* __restrict__ keep_ids,
                                               int* __restrict__ bar, int n, int kk) {
    __shared__ int lh[2048];
    __shared__ int s_d1, s_r1, s_c1, s_dA, s_rA, s_cA, s_dB, s_ntk, s_cnt3, s_bC, s_r2, s_lowD, s_lowR;
    __shared__ int s_base, s_cur;
    int t = threadIdx.x, b = blockIdx.x, lane = t & 63;
    int* h1 = gh;
    int* h2 = gh + 2048;
    int* h3 = gh + 4096;
    int* h4 = gh + 5120;
    int* h5 = gh + 5376;

    for (int i = b*1024 + t; i < NMAX; i += TKB*1024) degN[i] = 0;

    int nR = (n + 1023) & ~1023;
    lh[t] = 0; lh[t+1024] = 0;
    __syncthreads();
    for (int i = b*1024 + t; i < nR; i += TKB*1024) {
        bool act = (i < n);
        int bin = act ? (int)(keys[i] >> 21) : 0;
        histAdd(lh, bin, act, 11);
    }
    __syncthreads();
    { int c = lh[t]; if (c) atomicAdd(&h1[t], c); c = lh[t+1024]; if (c) atomicAdd(&h1[t+1024], c); }
    gridbar(&bar[0], TKB);
    selScan2048(h1, kk, &s_d1, &s_r1, &s_c1);
    int bstar = s_d1;

    lh[t] = 0; lh[t+1024] = 0;
    __syncthreads();
    for (int i = b*1024 + t; i < nR; i += TKB*1024) {
        bool act = false; int bin = 0;
        if (i < n) { unsigned key = keys[i]; act = ((int)(key >> 21) == bstar); bin = (int)((key >> 10) & 2047); }
        histAdd(lh, act ? bin : 0, act, 11);
    }
    __syncthreads();
    { int c = lh[t]; if (c) atomicAdd(&h2[t], c); c = lh[t+1024]; if (c) atomicAdd(&h2[t+1024], c); }
    gridbar(&bar[1], TKB);
    selScan2048(h2, s_r1, &s_dA, &s_rA, &s_cA);
    unsigned top21 = ((unsigned)bstar << 11) | (unsigned)s_dA;

    lh[t] = 0;
    __syncthreads();
    for (int i = b*1024 + t; i < nR; i += TKB*1024) {
        bool act = false; int bin = 0;
        if (i < n) { unsigned key = keys[i]; act = ((key >> 10) == top21); bin = (int)(key & 1023); }
        histAdd(lh, act ? bin : 0, act, 10);
    }
    __syncthreads();
    { int c = lh[t]; if (c) atomicAdd(&h3[t], c); }
    gridbar(&bar[2], TKB);
    selScan1024(h3, s_rA, &s_dB, &s_ntk, &s_cnt3);
    unsigned thresh = (top21 << 10) | (unsigned)s_dB;

    int cut;
    if (s_cnt3 == s_ntk) {
        // no boundary tie ambiguity: keep every key == thresh (common case for continuous scores)
        cut = n - 1;
    } else {
        if (t < 256) lh[t] = 0;
        __syncthreads();
        for (int i = b*1024 + t; i < n; i += TKB*1024)
            if (keys[i] == thresh) atomicAdd(&lh[i >> 8], 1);
        __syncthreads();
        if (t < 256) { int c = lh[t]; if (c) atomicAdd(&h4[t], c); }
        gridbar(&bar[3], TKB);
        prefixSel256(lh, h4, s_ntk, &s_bC, &s_r2);
        int bC = s_bC;

        if (t < 256) lh[t] = 0;
        __syncthreads();
        for (int i = b*1024 + t; i < n; i += TKB*1024)
            if (keys[i] == thresh && (i >> 8) == bC) atomicAdd(&lh[i & 255], 1);
        __syncthreads();
        if (t < 256) { int c = lh[t]; if (c) atomicAdd(&h5[t], c); }
        gridbar(&bar[4], TKB);
        prefixSel256(lh, h5, s_r2, &s_lowD, &s_lowR);
        cut = (bC << 8) | s_lowD;
    }

    {
        int cnt = 0;
        for (int base = b*1024; base < n; base += TKB*1024) {
            int i = base + t;
            if (i < n) {
                unsigned key = keys[i];
                cnt += (key > thresh) || (key == thresh && i <= cut);
            }
        }
        lh[t] = cnt; __syncthreads();
        for (int st = 512; st > 0; st >>= 1) { if (t < st) lh[t] += lh[t+st]; __syncthreads(); }
        if (t == 0) { s_base = atomicAdd(&selbuf[5], lh[0]); s_cur = 0; }
        __syncthreads();
        for (int base = b*1024; base < n; base += TKB*1024) {
            int i = base + t;
            bool keep = false;
            if (i < n) {
                unsigned key = keys[i];
                keep = (key > thresh) || (key == thresh && i <= cut);
            }
            unsigned long long m = __ballot(keep);
            int wcnt = __popcll(m);
            int wbase = 0;
            if (lane == 0 && wcnt) wbase = atomicAdd(&s_cur, wcnt);
            wbase = __shfl(wbase, 0);
            if (keep) {
                int slot = s_base + wbase + __popcll(m & ((1ULL << lane) - 1));
                remap[i] = slot; keep_ids[slot] = i;
            } else if (i < n) remap[i] = -1;
        }
    }
}

// ---------------------------------------------------------------- fused pool stats + next-layer GEMM + edge compact
// blocks [0,gb): stage pooled rows into LDS (stats fold free, coalesced scr write) + gemm for layer i+1
// blocks [gb,gb+EBLK): edge remap/compact (+next-layer degree/rank)
__global__ __launch_bounds__(128) void k_poolgemm(
        const float* __restrict__ AGGc, const float* __restrict__ score,
        const int* __restrict__ keep_ids, const int* __restrict__ remap,
        float* __restrict__ scr,
        const int* __restrict__ esrcP, const int* __restrict__ edstP,
        int* __restrict__ esrcN, int* __restrict__ edstN, int* __restrict__ erankN,
        const int* __restrict__ ecntP, int* __restrict__ ecntN, int* __restrict__ degN,
        const float* __restrict__ W, const float* __restrict__ V, const float* __restrict__ bias,
        float* __restrict__ HW, float* __restrict__ AGGn, int k, int gb, int do_gemm) {
    int b = blockIdx.x, t = threadIdx.x;
    __shared__ __align__(16) float ht[128*HTS];   // 10.2 KB -> ~15 blocks/CU
    if (b < gb) {
        int v0 = b * GRB;
        float mx = -3.402823e38f, sm = 0.f;
        #pragma unroll
        for (int it = 0; it < GRB; it++) {
            int r = v0 + it;
            bool valid = (r < k);
            int vv = keep_ids[valid ? r : (k - 1)];
            float val = AGGc[(size_t)vv*128 + t] * score[vv];
            if (!valid) val = 0.f;
            ht[t*HTS + it] = val;
            if (valid) { mx = fmaxf(mx, val); sm += val; }
        }
        scr[b*256 + t]       = mx;   // coalesced: thread t owns channel t
        scr[b*256 + 128 + t] = sm;
        if (!do_gemm) return;
        __syncthreads();
        float accW[GRB], accV[GRB];
        #pragma unroll
        for (int r = 0; r < GRB; r++) { accW[r] = 0.0f; accV[r] = 0.0f; }
        #pragma unroll 4
        for (int kk = 0; kk < 128; kk++) {
            float mw = W[kk*128 + t];
            float mv = V[kk*128 + t];
            const float* hp = &ht[kk*HTS];
            #pragma unroll
            for (int r4 = 0; r4 < GRB; r4 += 4) {
                float4 hq = *(const float4*)(hp + r4);
                accW[r4+0] += hq.x*mw;  accV[r4+0] += hq.x*mv;
                accW[r4+1] += hq.y*mw;  accV[r4+1] += hq.y*mv;
                accW[r4+2] += hq.z*mw;  accV[r4+2] += hq.z*mv;
                accW[r4+3] += hq.w*mw;  accV[r4+3] += hq.w*mv;
            }
        }
        float bb = bias[t];
        #pragma unroll
        for (int r = 0; r < GRB; r++) {
            int v = v0 + r;
            if (v >= k) break;
            HW[(size_t)v*128 + t]   = accW[r];
            AGGn[(size_t)v*128 + t] = accV[r] + bb;
        }
    } else {
        int eb = b - gb, lane = t & 63;
        int ec = *ecntP;
        int* red = (int*)ht;
        __shared__ int s_base, s_cur;
        int cnt = 0;
        for (int base = eb*128; base < ec; base += EBLK*128) {
            int e = base + t;
            if (e < ec) {
                int ns = remap[esrcP[e]], nd = remap[edstP[e]];
                cnt += (ns >= 0 && nd >= 0);
            }
        }
        red[t] = cnt; __syncthreads();
        for (int st = 64; st > 0; st >>= 1) { if (t < st) red[t] += red[t+st]; __syncthreads(); }
        if (t == 0) { s_base = atomicAdd(ecntN, red[0]); s_cur = 0; }
        __syncthreads();
        for (int base = eb*128; base < ec; base += EBLK*128) {
            int e = base + t;
            bool keep = false; int ns = 0, nd = 0;
            if (e < ec) {
                ns = remap[esrcP[e]]; nd = remap[edstP[e]];
                keep = (ns >= 0 && nd >= 0);
            }
            unsigned long long m = __ballot(keep);
            int wcnt = __popcll(m);
            int wbase = 0;
            if (lane == 0 && wcnt) wbase = atomicAdd(&s_cur, wcnt);
            wbase = __shfl(wbase, 0);
            if (keep) {
                int pos = s_base + wbase + __popcll(m & ((1ULL << lane) - 1));
                esrcN[pos] = ns; edstN[pos] = nd;
                erankN[pos] = atomicAdd(&degN[nd], 1);
            }
        }
    }
}

// ---------------------------------------------------------------- final-layer scratch reduce (parallel, 1 channel/block)
__global__ __launch_bounds__(256) void k_pred(const float* __restrict__ scr, float* __restrict__ rbuf,
                                              int gbP, int L) {
    poolReduceC(scr, rbuf, gbP, L, blockIdx.x);
}

// ---------------------------------------------------------------- MLP head
__global__ __launch_bounds__(320) void k_lin1(const float* __restrict__ rbuf,
                                              const float* __restrict__ w1,
                                              float* __restrict__ z1part) {
    int b = blockIdx.x, t = threadIdx.x;
    int j = t*4;
    float4 acc = make_float4(0.f, 0.f, 0.f, 0.f);
    int i0 = b*40;
    for (int r = 0; r < 40; r++) {
        int i = i0 + r;
        float rv = rbuf[i];
        if (i & 128) rv *= c_invk[i >> 8];
        float4 w = *(const float4*)(w1 + (size_t)i*1280 + j);
        acc.x += rv*w.x; acc.y += rv*w.y; acc.z += rv*w.z; acc.w += rv*w.w;
    }
    *(float4*)(z1part + b*1280 + j) = acc;
}

__global__ __launch_bounds__(320) void k_lin2(const float* __restrict__ z1part,
                                              const float* __restrict__ b1,
                                              const float* __restrict__ w2, const float* __restrict__ b2,
                                              const float* __restrict__ prelua, float* __restrict__ out) {
    int t = threadIdx.x, lane = t & 63, wid = t >> 6;
    float a = prelua[0];
    int j = t*4;
    float4 acc = make_float4(0.f, 0.f, 0.f, 0.f);
    for (int p = 0; p < LIN1B; p++) {
        float4 v = *(const float4*)(z1part + p*1280 + j);
        acc.x += v.x; acc.y += v.y; acc.z += v.z; acc.w += v.w;
    }
    float4 bb = *(const float4*)(b1 + j);
    float z0 = acc.x + bb.x; z0 = z0 > 0.f ? z0 : a*z0;
    float z1 = acc.y + bb.y; z1 = z1 > 0.f ? z1 : a*z1;
    float z2 = acc.z + bb.z; z2 = z2 > 0.f ? z2 : a*z2;
    float z3 = acc.w + bb.w; z3 = z3 > 0.f ? z3 : a*z3;
    float s[8];
    #pragma unroll
    for (int o = 0; o < 8; o++)
        s[o] = z0*w2[(j+0)*8+o] + z1*w2[(j+1)*8+o] + z2*w2[(j+2)*8+o] + z3*w2[(j+3)*8+o];
    #pragma unroll
    for (int off = 32; off > 0; off >>= 1)
        #pragma unroll
        for (int o = 0; o < 8; o++) s[o] += __shfl_down(s[o], off);
    __shared__ float sred[5][8];
    if (lane == 0)
        for (int o = 0; o < 8; o++) sred[wid][o] = s[o];
    __syncthreads();
    if (t == 0) {
        float zo[8];
        for (int o = 0; o < 8; o++) {
            float z = sred[0][o]+sred[1][o]+sred[2][o]+sred[3][o]+sred[4][o] + b2[o];
            zo[o] = z > 0.f ? z : a*z;
        }
        float mn = zo[0];
        for (int o = 1; o < 8; o++) mn = fminf(mn, zo[o]);
        float v[8], mx = -3.402823e38f;
        for (int o = 0; o < 8; o++) { v[o] = zo[o] - mn; mx = fmaxf(mx, v[o]); }
        float sm = 0.f;
        for (int o = 0; o < 8; o++) { v[o] = v[o] / mx; sm += v[o]; }
        for (int o = 0; o < 8; o++) out[o] = v[o] / sm;
    }
}

// ---------------------------------------------------------------- launch
extern "C" void kernel_launch(void* const* d_in, const int* in_sizes, int n_in,
                              void* d_out, int out_size, void* d_ws, size_t ws_size,
                              hipStream_t stream) {
    const float* x      = (const float*)d_in[0];
    const int*   eidx   = (const int*)  d_in[1];
    const float* W1     = (const float*)d_in[2];
    const float* V1     = (const float*)d_in[3];
    const float* Ws     = (const float*)d_in[4];
    const float* Vs     = (const float*)d_in[5];
    const float* convb  = (const float*)d_in[6];
    const float* bng    = (const float*)d_in[7];
    const float* bnb    = (const float*)d_in[8];
    const float* bnm    = (const float*)d_in[9];
    const float* bnv    = (const float*)d_in[10];
    const float* poolp  = (const float*)d_in[11];
    const float* prelua = (const float*)d_in[12];
    const float* w1     = (const float*)d_in[13];
    const float* b1     = (const float*)d_in[14];
    const float* w2     = (const float*)d_in[15];
    const float* b2     = (const float*)d_in[16];
    float* out = (float*)d_out;

    float* wsf  = (float*)d_ws;
    float* aggA   = wsf;                          // NMAX*128
    float* aggB   = aggA  + (size_t)NMAX*128;
    float* HW     = aggB  + (size_t)NMAX*128;
    float* dinv   = HW    + (size_t)NMAX*128;
    float* score  = dinv  + NMAX;
    float* rbuf   = score + NMAX;
    float* pnorm  = rbuf  + 2560;
    float* z1part = pnorm + 16;                   // LIN1B*1280
    float* scr    = z1part + LIN1B*1280;          // GBMAX*256 (coalesced: [block][256ch])
    unsigned* keys = (unsigned*)(scr + (size_t)GBMAX*256);
    int* esrcA  = (int*)(keys + NMAX);
    int* edstA  = esrcA + NEDGE;
    int* erankA = edstA + NEDGE;
    int* esrcB  = erankA + NEDGE;
    int* edstB  = esrcB + NEDGE;
    int* erankB = edstB + NEDGE;
    int* csr    = erankB + NEDGE;
    int* degA   = csr   + NEDGE;
    int* degB   = degA  + NMAX;
    int* ghist  = degB  + NMAX;                   // GHN
    int* offs   = ghist + GHN;
    int* remap  = offs  + NMAX;
    int* keep_ids = remap + NMAX;
    int* lbsum  = keep_ids + NMAX;                // SB*2
    int* ecnt   = lbsum + SB*2;                   // 16
    int* selbuf = ecnt  + 16;                     // 16
    int* tkc    = selbuf + 16;                    // 64

    static const int NS[10] = {40000,32000,25600,20480,16384,13108,10487,8390,6712,5370};
    static const int KS[10] = {32000,25600,20480,16384,13108,10487,8390,6712,5370,4296};

    hipMemsetAsync(degA, 0, (size_t)NMAX*sizeof(int), stream);
    k_init<<<2500, 256, 0, stream>>>(eidx, esrcA, edstA, erankA, poolp, rbuf, pnorm,
                                     ecnt, degA, tkc);

    for (int i = 0; i < 10; i++) {
        int n = NS[i], k = KS[i];
        int chunk = (n + SB - 1) / SB;
        int* esrcP  = (i & 1) ? esrcB  : esrcA;
        int* edstP  = (i & 1) ? edstB  : edstA;
        int* erankP = (i & 1) ? erankB : erankA;
        int* esrcN  = (i & 1) ? esrcA  : esrcB;
        int* edstN  = (i & 1) ? edstA  : edstB;
        int* erankN = (i & 1) ? erankA : erankB;
        int* degP   = (i & 1) ? degB : degA;
        int* degN   = (i & 1) ? degA : degB;
        float* AGGc = (i & 1) ? aggB : aggA;      // current layer features
        float* AGGn = (i & 1) ? aggA : aggB;      // next layer buffer

        int gbP = (i == 0) ? 0 : (KS[i-1] + GRB - 1) / GRB;
        k_presum<<<SB, 256, 0, stream>>>(degP, lbsum, n, chunk);
        k_scan<<<SB + PRB, 256, 0, stream>>>(degP, offs, dinv, ghist, selbuf,
                                             lbsum, scr, rbuf, n, chunk,
                                             gbP, i - 1);

        k_fill<<<FB, 128, 0, stream>>>(esrcP, edstP, erankP, offs, csr, &ecnt[i]);

        if (i == 0) {
            k_gather0<<<n, 128, 0, stream>>>(x, W1, V1, convb,
                                             bng, bnb, bnm, bnv, poolp, pnorm, prelua,
                                             offs, degP, dinv, csr, AGGc, score, keys);
        } else {
            k_gather<<<n, 128, 0, stream>>>(HW, AGGc, offs, degP, dinv, csr,
                                            bng, bnb, bnm, bnv, poolp, pnorm, prelua,
                                            score, keys, i);
        }

        k_topk<<<TKB, 1024, 0, stream>>>(keys, ghist, selbuf, degN,
                                         remap, keep_ids, tkc + i*5, n, k);

        int gb = (k + GRB - 1) / GRB;
        int do_gemm = (i < 9);
        int grid = gb + (do_gemm ? EBLK : 0);
        // gemm computes layer i+1: weights Ws[(i+1)-1] = Ws + i*16384, bias convb+(i+1)*128
        k_poolgemm<<<grid, 128, 0, stream>>>(AGGc, score, keep_ids, remap, scr,
                                             esrcP, edstP, esrcN, edstN, erankN,
                                             &ecnt[i], &ecnt[i+1], degN,
                                             Ws + (size_t)min(i,8)*16384,
                                             Vs + (size_t)min(i,8)*16384,
                                             convb + min(i+1,9)*128,
                                             HW, AGGn, k, gb, do_gemm);
    }

    k_pred<<<PRB, 256, 0, stream>>>(scr, rbuf, (KS[9] + GRB - 1) / GRB, 9);
    k_lin1<<<LIN1B, 320, 0, stream>>>(rbuf, w1, z1part);
    k_lin2<<<1, 320, 0, stream>>>(z1part, b1, w2, b2, prelua, out);
}

// Round 8
// 977.904 us; speedup vs baseline: 1.1199x; 1.0008x over previous
//
#include <hip/hip_runtime.h>
#include <hip/hip_bf16.h>

#define NEDGE 640000
#define NMAX  40000
#define SB    40      // scan blocks
#define PRB   256     // parallel pool-reduce blocks (1 channel each)
#define EBLK  512     // edge-compact blocks (128 thr)
#define FB    1280    // fill blocks (128 thr each)
#define LIN1B 64      // lin1 partial blocks
#define GRB   8       // gemm rows per block (halved per-block critical path, 2x grid TLP)
#define HTS   12      // ht row stride (GRB+4, 48B = multiple of 16B for float4 reads)
#define TKB   32      // fused top-k blocks
#define GHN   5632    // global hist ints (2048+2048+1024+256+256)
#define GBMAX 4096    // scr rows (>= max gemm blocks per layer = 4000)

// ---------------------------------------------------------------- helpers
__device__ inline unsigned orderKey(float s) {
    unsigned b = __float_as_uint(s);
    return (b & 0x80000000u) ? ~b : (b | 0x80000000u);
}

// ballot-dedup LDS histogram insert: O(1) atomics per distinct bin per wave
__device__ inline void histAdd(int* sh, int bin, bool act, int nbits) {
    unsigned long long mm = __ballot(act);
    for (int b = 0; b < nbits; b++) {
        unsigned long long bal = __ballot(act && ((bin >> b) & 1));
        mm &= ((bin >> b) & 1) ? bal : ~bal;
    }
    if (act) {
        int lane = threadIdx.x & 63;
        int leader = __ffsll(mm) - 1;
        if (lane == leader) atomicAdd(&sh[bin], __popcll(mm));
    }
}

// grid barrier for co-resident blocks (fresh counter per use, zeroed in k_init)
__device__ inline void gridbar(int* ctr, int target) {
    __syncthreads();
    if (threadIdx.x == 0) {
        __threadfence();
        __hip_atomic_fetch_add(ctr, 1, __ATOMIC_RELEASE, __HIP_MEMORY_SCOPE_AGENT);
        while (__hip_atomic_load(ctr, __ATOMIC_ACQUIRE, __HIP_MEMORY_SCOPE_AGENT) < target)
            __builtin_amdgcn_s_sleep(1);
        __threadfence();
    }
    __syncthreads();
}

__device__ inline int waveScanIncl(int v) {
    int lane = threadIdx.x & 63;
    #pragma unroll
    for (int off = 1; off < 64; off <<= 1) {
        int o = __shfl_up(v, off);
        if (lane >= off) v += o;
    }
    return v;
}

// find bin d such that suffix-sum S[d] >= rem > S[d+1] over 2048 bins, via shfl prefix scan.
// outR = rem - S[d+1]; outCnt = h[d]. 1024 threads, 2 bins/thread.
__device__ inline void selScan2048(const int* gh, int rem, int* outD, int* outR, int* outCnt) {
    __shared__ int wtot[16];
    __shared__ int s_T;
    int t = threadIdx.x, lane = t & 63, wid = t >> 6;
    int a0 = gh[2*t], a1 = gh[2*t+1];
    int s  = a0 + a1;
    int ws = waveScanIncl(s);
    if (lane == 63) wtot[wid] = ws;
    __syncthreads();
    if (t < 16) {
        int v = wtot[t];
        #pragma unroll
        for (int off = 1; off < 16; off <<= 1) { int o = __shfl_up(v, off); if (lane >= off) v += o; }
        wtot[t] = v;
        if (t == 15) s_T = v;
    }
    __syncthreads();
    int base = (wid > 0) ? wtot[wid-1] : 0;
    int inclPair = base + ws;          // inclusive prefix through bin 2t+1
    int P1 = inclPair - a1;            // exclusive prefix of bin 2t+1
    int P0 = P1 - a0;                  // exclusive prefix of bin 2t
    int Q = s_T - rem;
    if (a0 > 0 && P0 <= Q && Q < P0 + a0) { *outD = 2*t;   *outR = a0 - (Q - P0); *outCnt = a0; }
    if (a1 > 0 && P1 <= Q && Q < P1 + a1) { *outD = 2*t+1; *outR = a1 - (Q - P1); *outCnt = a1; }
    __syncthreads();
}

// same over 1024 bins, 1 bin/thread
__device__ inline void selScan1024(const int* gh, int rem, int* outD, int* outR, int* outCnt) {
    __shared__ int wtot[16];
    __shared__ int s_T;
    int t = threadIdx.x, lane = t & 63, wid = t >> 6;
    int a0 = gh[t];
    int ws = waveScanIncl(a0);
    if (lane == 63) wtot[wid] = ws;
    __syncthreads();
    if (t < 16) {
        int v = wtot[t];
        #pragma unroll
        for (int off = 1; off < 16; off <<= 1) { int o = __shfl_up(v, off); if (lane >= off) v += o; }
        wtot[t] = v;
        if (t == 15) s_T = v;
    }
    __syncthreads();
    int base = (wid > 0) ? wtot[wid-1] : 0;
    int P0 = base + ws - a0;           // exclusive prefix
    int Q = s_T - rem;
    if (a0 > 0 && P0 <= Q && Q < P0 + a0) { *outD = t; *outR = a0 - (Q - P0); *outCnt = a0; }
    __syncthreads();
}

__device__ inline void prefixSel256(int* lh, const int* gh, int rem, int* outD, int* outR) {
    int t = threadIdx.x;
    if (t < 256) lh[t] = gh[t];
    __syncthreads();
    for (int off = 1; off < 256; off <<= 1) {
        int v = 0;
        if (t < 256) v = lh[t] + ((t >= off) ? lh[t-off] : 0);
        __syncthreads();
        if (t < 256) lh[t] = v;
        __syncthreads();
    }
    if (t < 256) {
        int P = lh[t], Pp = (t == 0) ? 0 : lh[t-1];
        if (P >= rem && Pp < rem) { *outD = t; *outR = rem - Pp; }
    }
    __syncthreads();
}

// parallel pool-stat reduce over COALESCED scr layout [block][256ch]:
// one block per channel ch; threads stride the gemm-block axis r at scr[r*256+ch].
__device__ inline void poolReduceC(const float* __restrict__ scr, float* __restrict__ rbuf,
                                   int gbP, int L, int ch) {
    int t = threadIdx.x;
    bool isMax = ch < 128;
    float acc = isMax ? -3.402823e38f : 0.f;
    for (int r = t; r < gbP; r += 256) {
        float v = scr[(size_t)r*256 + ch];
        acc = isMax ? fmaxf(acc, v) : (acc + v);
    }
    __shared__ float red[256];
    red[t] = acc; __syncthreads();
    for (int st = 128; st > 0; st >>= 1) {
        if (t < st) red[t] = isMax ? fmaxf(red[t], red[t+st]) : (red[t] + red[t+st]);
        __syncthreads();
    }
    if (t == 0) rbuf[L*256 + ch] = red[0];
}

__device__ const float c_invk[10] = {
    1.0f/32000.0f, 1.0f/25600.0f, 1.0f/20480.0f, 1.0f/16384.0f, 1.0f/13108.0f,
    1.0f/10487.0f, 1.0f/8390.0f,  1.0f/6712.0f,  1.0f/5370.0f,  1.0f/4296.0f };

// ---------------------------------------------------------------- init (+ layer-0 degree count + ranks)
__global__ void k_init(const int* __restrict__ eidx, int* __restrict__ esrc,
                       int* __restrict__ edst, int* __restrict__ erank,
                       const float* __restrict__ poolp,
                       float* __restrict__ rbuf, float* __restrict__ pnorm,
                       int* __restrict__ ecnt, int* __restrict__ degA,
                       int* __restrict__ tkc) {
    int b = blockIdx.x, t = threadIdx.x;
    if (b < 10) {
        rbuf[b*256 + t] = (t < 128) ? -3.402823e38f : 0.0f;
        __shared__ float red[256];
        float v = 0.0f;
        if (t < 128) { float pv = poolp[b*128 + t]; v = pv*pv; }
        red[t] = v; __syncthreads();
        for (int s = 128; s > 0; s >>= 1) { if (t < s) red[t] += red[t+s]; __syncthreads(); }
        if (t == 0) pnorm[b] = sqrtf(red[0]);
    }
    if (b == 10 && t < 16) ecnt[t] = (t == 0) ? NEDGE : 0;
    if (b == 11 && t < 64) tkc[t] = 0;
    int e = b*256 + t;
    if (e < NEDGE) {
        int d = eidx[NEDGE + e];
        esrc[e] = eidx[e]; edst[e] = d;
        erank[e] = atomicAdd(&degA[d], 1);
    }
}

// ---------------------------------------------------------------- per-chunk sums (kernel-boundary replaces barrier)
__global__ __launch_bounds__(256) void k_presum(const int* __restrict__ deg,
                                                int* __restrict__ lbsum,
                                                int n, int chunk) {
    int b = blockIdx.x, t = threadIdx.x;
    __shared__ int red[256];
    int start = b*chunk, end = min(start + chunk, n);
    int s = 0;
    for (int i = start + t; i < end; i += 256) s += deg[i];
    red[t] = s; __syncthreads();
    for (int st = 128; st > 0; st >>= 1) { if (t < st) red[t] += red[t+st]; __syncthreads(); }
    if (t == 0) lbsum[b] = red[0];
}

// ---------------------------------------------------------------- scan + parallel pool reduce
// blocks [0,SB): scan; blocks [SB,SB+PRB): reduce previous layer's pool scratch (1 channel each)
__global__ void k_scan(const int* __restrict__ deg,
                       int* __restrict__ offs, float* __restrict__ dinv,
                       int* __restrict__ ghist, int* __restrict__ selbuf,
                       const int* __restrict__ lbsum,
                       const float* __restrict__ scr, float* __restrict__ rbuf,
                       int n, int chunk, int gbP, int prevL) {
    int b = blockIdx.x, t = threadIdx.x, lane = t & 63, wid = t >> 6;
    if (b >= SB) {
        if (gbP > 0) poolReduceC(scr, rbuf, gbP, prevL, b - SB);
        return;
    }
    __shared__ int s_excl;
    __shared__ int wsum[4];
    __shared__ int s_carry;
    __shared__ int s_sums[SB];
    if (b == 0) {
        for (int jj = t; jj < GHN; jj += 256) ghist[jj] = 0;
        if (t == 0) { selbuf[2] = 0; selbuf[5] = 0; }
    }
    if (t < SB) s_sums[t] = lbsum[t];
    __syncthreads();
    if (t == 0) {
        int excl = 0;
        for (int p = 0; p < b; p++) excl += s_sums[p];
        s_excl = excl;
    }
    __syncthreads();
    if (t == 0) s_carry = s_excl;
    __syncthreads();
    int start = b*chunk, end = min(start + chunk, n);
    for (int base = start; base < end; base += 256) {
        int i = base + t;
        int d = (i < end) ? deg[i] : 0;
        int incl = d;
        for (int off = 1; off < 64; off <<= 1) {
            int o = __shfl_up(incl, off);
            if (lane >= off) incl += o;
        }
        if (lane == 63) wsum[wid] = incl;
        __syncthreads();
        if (t == 0) { int c = s_carry; for (int w = 0; w < 4; w++) { int tmp = wsum[w]; wsum[w] = c; c += tmp; } s_carry = c; }
        __syncthreads();
        int p = wsum[wid] + incl - d;
        if (i < end) {
            offs[i] = p;
            dinv[i] = (d > 0) ? 1.0f/sqrtf((float)d) : 0.0f;
        }
        __syncthreads();
    }
}

// ---------------------------------------------------------------- slim CSR fill (rank-based, no atomics, no LDS)
__global__ __launch_bounds__(128) void k_fill(const int* __restrict__ esrc, const int* __restrict__ edst,
                                              const int* __restrict__ erank, const int* __restrict__ offs,
                                              int* __restrict__ csr, const int* __restrict__ ecnt) {
    int ec = *ecnt;
    for (int e = blockIdx.x*128 + threadIdx.x; e < ec; e += FB*128)
        csr[offs[edst[e]] + erank[e]] = esrc[e];
}

// ---------------------------------------------------------------- layer-0 fused node update
__global__ __launch_bounds__(128) void k_gather0(
    const float* __restrict__ x, const float* __restrict__ W1, const float* __restrict__ V1,
    const float* __restrict__ convb,
    const float* __restrict__ bng, const float* __restrict__ bnb,
    const float* __restrict__ bnm, const float* __restrict__ bnv,
    const float* __restrict__ poolp, const float* __restrict__ pnorm,
    const float* __restrict__ prelua,
    const int* __restrict__ offs, const int* __restrict__ deg, const float* __restrict__ dinv,
    const int* __restrict__ csr,
    float* __restrict__ AGG, float* __restrict__ score, unsigned* __restrict__ keys) {
    int v = blockIdx.x, j = threadIdx.x;
    __shared__ float red[128];
    int off = offs[v], dg = deg[v];
    float accs = 0.0f;
    for (int c = j; c < dg; c += 128) { int s = csr[off + c]; accs += x[s]*dinv[s]; }
    red[j] = accs; __syncthreads();
    for (int st = 64; st > 0; st >>= 1) { if (j < st) red[j] += red[j+st]; __syncthreads(); }
    float aggs = red[0] * dinv[v];
    __syncthreads();
    float h2 = aggs*W1[j] + x[v]*V1[j] + convb[j];
    h2 = fmaxf(h2, 0.0f);
    float scale = bng[j] / sqrtf(bnv[j] + 1e-5f);
    h2 = (h2 - bnm[j])*scale + bnb[j];
    float a = prelua[0];
    h2 = (h2 > 0.0f) ? h2 : a*h2;
    AGG[v*128 + j] = h2;
    red[j] = h2 * poolp[j]; __syncthreads();
    for (int st = 64; st > 0; st >>= 1) { if (j < st) red[j] += red[j+st]; __syncthreads(); }
    if (j == 0) {
        float sc = tanhf(red[0] / pnorm[0]);
        score[v] = sc;
        keys[v]  = orderKey(sc);
    }
}

// ---------------------------------------------------------------- generic fused gather + update + score
__global__ __launch_bounds__(128) void k_gather(
    const float* __restrict__ HW, float* __restrict__ AGG,
    const int* __restrict__ offs, const int* __restrict__ deg, const float* __restrict__ dinv,
    const int* __restrict__ csr,
    const float* __restrict__ bng, const float* __restrict__ bnb,
    const float* __restrict__ bnm, const float* __restrict__ bnv,
    const float* __restrict__ poolp, const float* __restrict__ pnorm,
    const float* __restrict__ prelua,
    float* __restrict__ score, unsigned* __restrict__ keys, int layer) {
    int v = blockIdx.x, j = threadIdx.x;
    __shared__ int   s_src[128];
    __shared__ float s_dv[128];
    __shared__ float red[128];
    int off = offs[v], dg = deg[v];
    float acc = 0.0f;
    for (int base = 0; base < dg; base += 128) {
        int cnt = min(128, dg - base);
        if (j < cnt) { int s = csr[off + base + j]; s_src[j] = s; s_dv[j] = dinv[s]; }
        __syncthreads();
        for (int c = 0; c < cnt; c++) acc += HW[s_src[c]*128 + j] * s_dv[c];
        __syncthreads();
    }
    int gj = layer*128 + j;
    float h2 = AGG[v*128 + j] + acc*dinv[v];
    h2 = fmaxf(h2, 0.0f);
    float scale = bng[gj] / sqrtf(bnv[gj] + 1e-5f);
    h2 = (h2 - bnm[gj])*scale + bnb[gj];
    float a = prelua[0];
    h2 = (h2 > 0.0f) ? h2 : a*h2;
    AGG[v*128 + j] = h2;
    red[j] = h2 * poolp[gj]; __syncthreads();
    for (int st = 64; st > 0; st >>= 1) { if (j < st) red[j] += red[j+st]; __syncthreads(); }
    if (j == 0) {
        float sc = tanhf(red[0] / pnorm[layer]);
        score[v] = sc;
        keys[v]  = orderKey(sc);
    }
}

// ---------------------------------------------------------------- fused top-k, all phases grid-parallel
__global__ __launch_bounds__(1024) void k_topk(const unsigned* __restrict__ keys,
                                               int* __restrict__ gh, int* __restrict__ selbuf,
                                               int* __restrict__ degN,
                                               int* __restrict__ remap, int* __restrict__ keep_ids,
                                               int* __restrict__ bar, int n, int kk) {
    __shared__ int lh[2048];
    __shared__ int s_d1, s_r1, s_c1, s_dA, s_rA, s_cA, s_dB, s_ntk, s_cnt3, s_bC, s_r2, s_lowD, s_lowR;
    __shared__ int s_base, s_cur;
    int t = threadIdx.x, b = blockIdx.x, lane = t & 63;
    int* h1 = gh;
    int* h2 = gh + 2048;
    int* h3 = gh + 4096;
    int* h4 = gh + 5120;
    int* h5 = gh + 5376;

    for (int i = b*1024 + t; i < NMAX; i += TKB*1024) degN[i] = 0;

    int nR = (n + 1023) & ~1023;
    lh[t] = 0; lh[t+1024] = 0;
    __syncthreads();
    for (int i = b*1024 + t; i < nR; i += TKB*1024) {
        bool act = (i < n);
        int bin = act ? (int)(keys[i] >> 21) : 0;
        histAdd(lh, bin, act, 11);
    }
    __syncthreads();
    { int c = lh[t]; if (c) atomicAdd(&h1[t], c); c = lh[t+1024]; if (c) atomicAdd(&h1[t+1024], c); }
    gridbar(&bar[0], TKB);
    selScan2048(h1, kk, &s_d1, &s_r1, &s_c1);
    int bstar = s_d1;

    lh[t] = 0; lh[t+1024] = 0;
    __syncthreads();
    for (int i = b*1024 + t; i < nR; i += TKB*1024) {
        bool act = false; int bin = 0;
        if (i < n) { unsigned key = keys[i]; act = ((int)(key >> 21) == bstar); bin = (int)((key >> 10) & 2047); }
        histAdd(lh, act ? bin : 0, act, 11);
    }
    __syncthreads();
    { int c = lh[t]; if (c) atomicAdd(&h2[t], c); c = lh[t+1024]; if (c) atomicAdd(&h2[t+1024], c); }
    gridbar(&bar[1], TKB);
    selScan2048(h2, s_r1, &s_dA, &s_rA, &s_cA);
    unsigned top21 = ((unsigned)bstar << 11) | (unsigned)s_dA;

    lh[t] = 0;
    __syncthreads();
    for (int i = b*1024 + t; i < nR; i += TKB*1024) {
        bool act = false; int bin = 0;
        if (i < n) { unsigned key = keys[i]; act = ((key >> 10) == top21); bin = (int)(key & 1023); }
        histAdd(lh, act ? bin : 0, act, 10);
    }
    __syncthreads();
    { int c = lh[t]; if (c) atomicAdd(&h3[t], c); }
    gridbar(&bar[2], TKB);
    selScan1024(h3, s_rA, &s_dB, &s_ntk, &s_cnt3);
    unsigned thresh = (top21 << 10) | (unsigned)s_dB;

    int cut;
    if (s_cnt3 == s_ntk) {
        // no boundary tie ambiguity: keep every key == thresh (common case for continuous scores)
        cut = n - 1;
    } else {
        if (t < 256) lh[t] = 0;
        __syncthreads();
        for (int i = b*1024 + t; i < n; i += TKB*1024)
            if (keys[i] == thresh) atomicAdd(&lh[i >> 8], 1);
        __syncthreads();
        if (t < 256) { int c = lh[t]; if (c) atomicAdd(&h4[t], c); }
        gridbar(&bar[3], TKB);
        prefixSel256(lh, h4, s_ntk, &s_bC, &s_r2);
        int bC = s_bC;

        if (t < 256) lh[t] = 0;
        __syncthreads();
        for (int i = b*1024 + t; i < n; i += TKB*1024)
            if (keys[i] == thresh && (i >> 8) == bC) atomicAdd(&lh[i & 255], 1);
        __syncthreads();
        if (t < 256) { int c = lh[t]; if (c) atomicAdd(&h5[t], c); }
        gridbar(&bar[4], TKB);
        prefixSel256(lh, h5, s_r2, &s_lowD, &s_lowR);
        cut = (bC << 8) | s_lowD;
    }

    {
        int cnt = 0;
        for (int base = b*1024; base < n; base += TKB*1024) {
            int i = base + t;
            if (i < n) {
                unsigned key = keys[i];
                cnt += (key > thresh) || (key == thresh && i <= cut);
            }
        }
        lh[t] = cnt; __syncthreads();
        for (int st = 512; st > 0; st >>= 1) { if (t < st) lh[t] += lh[t+st]; __syncthreads(); }
        if (t == 0) { s_base = atomicAdd(&selbuf[5], lh[0]); s_cur = 0; }
        __syncthreads();
        for (int base = b*1024; base < n; base += TKB*1024) {
            int i = base + t;
            bool keep = false;
            if (i < n) {
                unsigned key = keys[i];
                keep = (key > thresh) || (key == thresh && i <= cut);
            }
            unsigned long long m = __ballot(keep);
            int wcnt = __popcll(m);
            int wbase = 0;
            if (lane == 0 && wcnt) wbase = atomicAdd(&s_cur, wcnt);
            wbase = __shfl(wbase, 0);
            if (keep) {
                int slot = s_base + wbase + __popcll(m & ((1ULL << lane) - 1));
                remap[i] = slot; keep_ids[slot] = i;
            } else if (i < n) remap[i] = -1;
        }
    }
}

// ---------------------------------------------------------------- fused pool stats + next-layer GEMM + edge compact
// blocks [0,gb): stage pooled rows into LDS (stats fold free, coalesced scr write) + gemm for layer i+1
// blocks [gb,gb+EBLK): edge remap/compact (+next-layer degree/rank)
__global__ __launch_bounds__(128) void k_poolgemm(
        const float* __restrict__ AGGc, const float* __restrict__ score,
        const int* __restrict__ keep_ids, const int* __restrict__ remap,
        float* __restrict__ scr,
        const int* __restrict__ esrcP, const int* __restrict__ edstP,
        int* __restrict__ esrcN, int* __restrict__ edstN, int* __restrict__ erankN,
        const int* __restrict__ ecntP, int* __restrict__ ecntN, int* __restrict__ degN,
        const float* __restrict__ W, const float* __restrict__ V, const float* __restrict__ bias,
        float* __restrict__ HW, float* __restrict__ AGGn, int k, int gb, int do_gemm) {
    int b = blockIdx.x, t = threadIdx.x;
    __shared__ __align__(16) float ht[128*HTS];   // 6.1 KB -> ~26 blocks/CU LDS-cap
    if (b < gb) {
        int v0 = b * GRB;
        float mx = -3.402823e38f, sm = 0.f;
        #pragma unroll
        for (int it = 0; it < GRB; it++) {
            int r = v0 + it;
            bool valid = (r < k);
            int vv = keep_ids[valid ? r : (k - 1)];
            float val = AGGc[(size_t)vv*128 + t] * score[vv];
            if (!valid) val = 0.f;
            ht[t*HTS + it] = val;
            if (valid) { mx = fmaxf(mx, val); sm += val; }
        }
        scr[b*256 + t]       = mx;   // coalesced: thread t owns channel t
        scr[b*256 + 128 + t] = sm;
        if (!do_gemm) return;
        __syncthreads();
        float accW[GRB], accV[GRB];
        #pragma unroll
        for (int r = 0; r < GRB; r++) { accW[r] = 0.0f; accV[r] = 0.0f; }
        #pragma unroll 4
        for (int kk = 0; kk < 128; kk++) {
            float mw = W[kk*128 + t];
            float mv = V[kk*128 + t];
            const float* hp = &ht[kk*HTS];
            #pragma unroll
            for (int r4 = 0; r4 < GRB; r4 += 4) {
                float4 hq = *(const float4*)(hp + r4);
                accW[r4+0] += hq.x*mw;  accV[r4+0] += hq.x*mv;
                accW[r4+1] += hq.y*mw;  accV[r4+1] += hq.y*mv;
                accW[r4+2] += hq.z*mw;  accV[r4+2] += hq.z*mv;
                accW[r4+3] += hq.w*mw;  accV[r4+3] += hq.w*mv;
            }
        }
        float bb = bias[t];
        #pragma unroll
        for (int r = 0; r < GRB; r++) {
            int v = v0 + r;
            if (v >= k) break;
            HW[(size_t)v*128 + t]   = accW[r];
            AGGn[(size_t)v*128 + t] = accV[r] + bb;
        }
    } else {
        int eb = b - gb, lane = t & 63;
        int ec = *ecntP;
        int* red = (int*)ht;
        __shared__ int s_base, s_cur;
        int cnt = 0;
        for (int base = eb*128; base < ec; base += EBLK*128) {
            int e = base + t;
            if (e < ec) {
                int ns = remap[esrcP[e]], nd = remap[edstP[e]];
                cnt += (ns >= 0 && nd >= 0);
            }
        }
        red[t] = cnt; __syncthreads();
        for (int st = 64; st > 0; st >>= 1) { if (t < st) red[t] += red[t+st]; __syncthreads(); }
        if (t == 0) { s_base = atomicAdd(ecntN, red[0]); s_cur = 0; }
        __syncthreads();
        for (int base = eb*128; base < ec; base += EBLK*128) {
            int e = base + t;
            bool keep = false; int ns = 0, nd = 0;
            if (e < ec) {
                ns = remap[esrcP[e]]; nd = remap[edstP[e]];
                keep = (ns >= 0 && nd >= 0);
            }
            unsigned long long m = __ballot(keep);
            int wcnt = __popcll(m);
            int wbase = 0;
            if (lane == 0 && wcnt) wbase = atomicAdd(&s_cur, wcnt);
            wbase = __shfl(wbase, 0);
            if (keep) {
                int pos = s_base + wbase + __popcll(m & ((1ULL << lane) - 1));
                esrcN[pos] = ns; edstN[pos] = nd;
                erankN[pos] = atomicAdd(&degN[nd], 1);
            }
        }
    }
}

// ---------------------------------------------------------------- final-layer scratch reduce (parallel, 1 channel/block)
__global__ __launch_bounds__(256) void k_pred(const float* __restrict__ scr, float* __restrict__ rbuf,
                                              int gbP, int L) {
    poolReduceC(scr, rbuf, gbP, L, blockIdx.x);
}

// ---------------------------------------------------------------- MLP head
__global__ __launch_bounds__(320) void k_lin1(const float* __restrict__ rbuf,
                                              const float* __restrict__ w1,
                                              float* __restrict__ z1part) {
    int b = blockIdx.x, t = threadIdx.x;
    int j = t*4;
    float4 acc = make_float4(0.f, 0.f, 0.f, 0.f);
    int i0 = b*40;
    for (int r = 0; r < 40; r++) {
        int i = i0 + r;
        float rv = rbuf[i];
        if (i & 128) rv *= c_invk[i >> 8];
        float4 w = *(const float4*)(w1 + (size_t)i*1280 + j);
        acc.x += rv*w.x; acc.y += rv*w.y; acc.z += rv*w.z; acc.w += rv*w.w;
    }
    *(float4*)(z1part + b*1280 + j) = acc;
}

__global__ __launch_bounds__(320) void k_lin2(const float* __restrict__ z1part,
                                              const float* __restrict__ b1,
                                              const float* __restrict__ w2, const float* __restrict__ b2,
                                              const float* __restrict__ prelua, float* __restrict__ out) {
    int t = threadIdx.x, lane = t & 63, wid = t >> 6;
    float a = prelua[0];
    int j = t*4;
    float4 acc = make_float4(0.f, 0.f, 0.f, 0.f);
    for (int p = 0; p < LIN1B; p++) {
        float4 v = *(const float4*)(z1part + p*1280 + j);
        acc.x += v.x; acc.y += v.y; acc.z += v.z; acc.w += v.w;
    }
    float4 bb = *(const float4*)(b1 + j);
    float z0 = acc.x + bb.x; z0 = z0 > 0.f ? z0 : a*z0;
    float z1 = acc.y + bb.y; z1 = z1 > 0.f ? z1 : a*z1;
    float z2 = acc.z + bb.z; z2 = z2 > 0.f ? z2 : a*z2;
    float z3 = acc.w + bb.w; z3 = z3 > 0.f ? z3 : a*z3;
    float s[8];
    #pragma unroll
    for (int o = 0; o < 8; o++)
        s[o] = z0*w2[(j+0)*8+o] + z1*w2[(j+1)*8+o] + z2*w2[(j+2)*8+o] + z3*w2[(j+3)*8+o];
    #pragma unroll
    for (int off = 32; off > 0; off >>= 1)
        #pragma unroll
        for (int o = 0; o < 8; o++) s[o] += __shfl_down(s[o], off);
    __shared__ float sred[5][8];
    if (lane == 0)
        for (int o = 0; o < 8; o++) sred[wid][o] = s[o];
    __syncthreads();
    if (t == 0) {
        float zo[8];
        for (int o = 0; o < 8; o++) {
            float z = sred[0][o]+sred[1][o]+sred[2][o]+sred[3][o]+sred[4][o] + b2[o];
            zo[o] = z > 0.f ? z : a*z;
        }
        float mn = zo[0];
        for (int o = 1; o < 8; o++) mn = fminf(mn, zo[o]);
        float v[8], mx = -3.402823e38f;
        for (int o = 0; o < 8; o++) { v[o] = zo[o] - mn; mx = fmaxf(mx, v[o]); }
        float sm = 0.f;
        for (int o = 0; o < 8; o++) { v[o] = v[o] / mx; sm += v[o]; }
        for (int o = 0; o < 8; o++) out[o] = v[o] / sm;
    }
}

// ---------------------------------------------------------------- launch
extern "C" void kernel_launch(void* const* d_in, const int* in_sizes, int n_in,
                              void* d_out, int out_size, void* d_ws, size_t ws_size,
                              hipStream_t stream) {
    const float* x      = (const float*)d_in[0];
    const int*   eidx   = (const int*)  d_in[1];
    const float* W1     = (const float*)d_in[2];
    const float* V1     = (const float*)d_in[3];
    const float* Ws     = (const float*)d_in[4];
    const float* Vs     = (const float*)d_in[5];
    const float* convb  = (const float*)d_in[6];
    const float* bng    = (const float*)d_in[7];
    const float* bnb    = (const float*)d_in[8];
    const float* bnm    = (const float*)d_in[9];
    const float* bnv    = (const float*)d_in[10];
    const float* poolp  = (const float*)d_in[11];
    const float* prelua = (const float*)d_in[12];
    const float* w1     = (const float*)d_in[13];
    const float* b1     = (const float*)d_in[14];
    const float* w2     = (const float*)d_in[15];
    const float* b2     = (const float*)d_in[16];
    float* out = (float*)d_out;

    float* wsf  = (float*)d_ws;
    float* aggA   = wsf;                          // NMAX*128
    float* aggB   = aggA  + (size_t)NMAX*128;
    float* HW     = aggB  + (size_t)NMAX*128;
    float* dinv   = HW    + (size_t)NMAX*128;
    float* score  = dinv  + NMAX;
    float* rbuf   = score + NMAX;
    float* pnorm  = rbuf  + 2560;
    float* z1part = pnorm + 16;                   // LIN1B*1280
    float* scr    = z1part + LIN1B*1280;          // GBMAX*256 (coalesced: [block][256ch])
    unsigned* keys = (unsigned*)(scr + (size_t)GBMAX*256);
    int* esrcA  = (int*)(keys + NMAX);
    int* edstA  = esrcA + NEDGE;
    int* erankA = edstA + NEDGE;
    int* esrcB  = erankA + NEDGE;
    int* edstB  = esrcB + NEDGE;
    int* erankB = edstB + NEDGE;
    int* csr    = erankB + NEDGE;
    int* degA   = csr   + NEDGE;
    int* degB   = degA  + NMAX;
    int* ghist  = degB  + NMAX;                   // GHN
    int* offs   = ghist + GHN;
    int* remap  = offs  + NMAX;
    int* keep_ids = remap + NMAX;
    int* lbsum  = keep_ids + NMAX;                // SB*2
    int* ecnt   = lbsum + SB*2;                   // 16
    int* selbuf = ecnt  + 16;                     // 16
    int* tkc    = selbuf + 16;                    // 64

    static const int NS[10] = {40000,32000,25600,20480,16384,13108,10487,8390,6712,5370};
    static const int KS[10] = {32000,25600,20480,16384,13108,10487,8390,6712,5370,4296};

    hipMemsetAsync(degA, 0, (size_t)NMAX*sizeof(int), stream);
    k_init<<<2500, 256, 0, stream>>>(eidx, esrcA, edstA, erankA, poolp, rbuf, pnorm,
                                     ecnt, degA, tkc);

    for (int i = 0; i < 10; i++) {
        int n = NS[i], k = KS[i];
        int chunk = (n + SB - 1) / SB;
        int* esrcP  = (i & 1) ? esrcB  : esrcA;
        int* edstP  = (i & 1) ? edstB  : edstA;
        int* erankP = (i & 1) ? erankB : erankA;
        int* esrcN  = (i & 1) ? esrcA  : esrcB;
        int* edstN  = (i & 1) ? edstA  : edstB;
        int* erankN = (i & 1) ? erankA : erankB;
        int* degP   = (i & 1) ? degB : degA;
        int* degN   = (i & 1) ? degA : degB;
        float* AGGc = (i & 1) ? aggB : aggA;      // current layer features
        float* AGGn = (i & 1) ? aggA : aggB;      // next layer buffer

        int gbP = (i == 0) ? 0 : (KS[i-1] + GRB - 1) / GRB;
        k_presum<<<SB, 256, 0, stream>>>(degP, lbsum, n, chunk);
        k_scan<<<SB + PRB, 256, 0, stream>>>(degP, offs, dinv, ghist, selbuf,
                                             lbsum, scr, rbuf, n, chunk,
                                             gbP, i - 1);

        k_fill<<<FB, 128, 0, stream>>>(esrcP, edstP, erankP, offs, csr, &ecnt[i]);

        if (i == 0) {
            k_gather0<<<n, 128, 0, stream>>>(x, W1, V1, convb,
                                             bng, bnb, bnm, bnv, poolp, pnorm, prelua,
                                             offs, degP, dinv, csr, AGGc, score, keys);
        } else {
            k_gather<<<n, 128, 0, stream>>>(HW, AGGc, offs, degP, dinv, csr,
                                            bng, bnb, bnm, bnv, poolp, pnorm, prelua,
                                            score, keys, i);
        }

        k_topk<<<TKB, 1024, 0, stream>>>(keys, ghist, selbuf, degN,
                                         remap, keep_ids, tkc + i*5, n, k);

        int gb = (k + GRB - 1) / GRB;
        int do_gemm = (i < 9);
        int grid = gb + (do_gemm ? EBLK : 0);
        // gemm computes layer i+1: weights Ws[(i+1)-1] = Ws + i*16384, bias convb+(i+1)*128
        k_poolgemm<<<grid, 128, 0, stream>>>(AGGc, score, keep_ids, remap, scr,
                                             esrcP, edstP, esrcN, edstN, erankN,
                                             &ecnt[i], &ecnt[i+1], degN,
                                             Ws + (size_t)min(i,8)*16384,
                                             Vs + (size_t)min(i,8)*16384,
                                             convb + min(i+1,9)*128,
                                             HW, AGGn, k, gb, do_gemm);
    }

    k_pred<<<PRB, 256, 0, stream>>>(scr, rbuf, (KS[9] + GRB - 1) / GRB, 9);
    k_lin1<<<LIN1B, 320, 0, stream>>>(rbuf, w1, z1part);
    k_lin2<<<1, 320, 0, stream>>>(z1part, b1, w2, b2, prelua, out);
}

// Round 9
// 975.486 us; speedup vs baseline: 1.1227x; 1.0025x over previous
//
#include <hip/hip_runtime.h>
#include <hip/hip_bf16.h>

#define NEDGE 640000
#define NMAX  40000
#define SB    40      // scan blocks
#define PRB   256     // parallel pool-reduce blocks (1 channel each)
#define EBLK  512     // edge-compact blocks (256 thr)
#define FB    1280    // fill blocks (128 thr each)
#define LIN1B 64      // lin1 partial blocks
#define TKB   64      // fused top-k blocks
#define GHN   5632    // global hist ints (2048+2048+1024+256+256)
#define GBMAX 4096    // scr rows (>= max gemm blocks per layer = 2000)

// ---------------------------------------------------------------- helpers
__device__ inline unsigned orderKey(float s) {
    unsigned b = __float_as_uint(s);
    return (b & 0x80000000u) ? ~b : (b | 0x80000000u);
}

// ballot-dedup LDS histogram insert: O(1) atomics per distinct bin per wave
__device__ inline void histAdd(int* sh, int bin, bool act, int nbits) {
    unsigned long long mm = __ballot(act);
    for (int b = 0; b < nbits; b++) {
        unsigned long long bal = __ballot(act && ((bin >> b) & 1));
        mm &= ((bin >> b) & 1) ? bal : ~bal;
    }
    if (act) {
        int lane = threadIdx.x & 63;
        int leader = __ffsll(mm) - 1;
        if (lane == leader) atomicAdd(&sh[bin], __popcll(mm));
    }
}

// grid barrier for co-resident blocks (fresh counter per use, zeroed in k_init)
__device__ inline void gridbar(int* ctr, int target) {
    __syncthreads();
    if (threadIdx.x == 0) {
        __threadfence();
        __hip_atomic_fetch_add(ctr, 1, __ATOMIC_RELEASE, __HIP_MEMORY_SCOPE_AGENT);
        while (__hip_atomic_load(ctr, __ATOMIC_ACQUIRE, __HIP_MEMORY_SCOPE_AGENT) < target)
            __builtin_amdgcn_s_sleep(1);
        __threadfence();
    }
    __syncthreads();
}

__device__ inline int waveScanIncl(int v) {
    int lane = threadIdx.x & 63;
    #pragma unroll
    for (int off = 1; off < 64; off <<= 1) {
        int o = __shfl_up(v, off);
        if (lane >= off) v += o;
    }
    return v;
}

// find bin d such that suffix-sum S[d] >= rem > S[d+1] over 2048 bins, via shfl prefix scan.
// outR = rem - S[d+1]; outCnt = h[d]. 1024 threads, 2 bins/thread.
__device__ inline void selScan2048(const int* gh, int rem, int* outD, int* outR, int* outCnt) {
    __shared__ int wtot[16];
    __shared__ int s_T;
    int t = threadIdx.x, lane = t & 63, wid = t >> 6;
    int a0 = gh[2*t], a1 = gh[2*t+1];
    int s  = a0 + a1;
    int ws = waveScanIncl(s);
    if (lane == 63) wtot[wid] = ws;
    __syncthreads();
    if (t < 16) {
        int v = wtot[t];
        #pragma unroll
        for (int off = 1; off < 16; off <<= 1) { int o = __shfl_up(v, off); if (lane >= off) v += o; }
        wtot[t] = v;
        if (t == 15) s_T = v;
    }
    __syncthreads();
    int base = (wid > 0) ? wtot[wid-1] : 0;
    int inclPair = base + ws;          // inclusive prefix through bin 2t+1
    int P1 = inclPair - a1;            // exclusive prefix of bin 2t+1
    int P0 = P1 - a0;                  // exclusive prefix of bin 2t
    int Q = s_T - rem;
    if (a0 > 0 && P0 <= Q && Q < P0 + a0) { *outD = 2*t;   *outR = a0 - (Q - P0); *outCnt = a0; }
    if (a1 > 0 && P1 <= Q && Q < P1 + a1) { *outD = 2*t+1; *outR = a1 - (Q - P1); *outCnt = a1; }
    __syncthreads();
}

// same over 1024 bins, 1 bin/thread
__device__ inline void selScan1024(const int* gh, int rem, int* outD, int* outR, int* outCnt) {
    __shared__ int wtot[16];
    __shared__ int s_T;
    int t = threadIdx.x, lane = t & 63, wid = t >> 6;
    int a0 = gh[t];
    int ws = waveScanIncl(a0);
    if (lane == 63) wtot[wid] = ws;
    __syncthreads();
    if (t < 16) {
        int v = wtot[t];
        #pragma unroll
        for (int off = 1; off < 16; off <<= 1) { int o = __shfl_up(v, off); if (lane >= off) v += o; }
        wtot[t] = v;
        if (t == 15) s_T = v;
    }
    __syncthreads();
    int base = (wid > 0) ? wtot[wid-1] : 0;
    int P0 = base + ws - a0;           // exclusive prefix
    int Q = s_T - rem;
    if (a0 > 0 && P0 <= Q && Q < P0 + a0) { *outD = t; *outR = a0 - (Q - P0); *outCnt = a0; }
    __syncthreads();
}

__device__ inline void prefixSel256(int* lh, const int* gh, int rem, int* outD, int* outR) {
    int t = threadIdx.x;
    if (t < 256) lh[t] = gh[t];
    __syncthreads();
    for (int off = 1; off < 256; off <<= 1) {
        int v = 0;
        if (t < 256) v = lh[t] + ((t >= off) ? lh[t-off] : 0);
        __syncthreads();
        if (t < 256) lh[t] = v;
        __syncthreads();
    }
    if (t < 256) {
        int P = lh[t], Pp = (t == 0) ? 0 : lh[t-1];
        if (P >= rem && Pp < rem) { *outD = t; *outR = rem - Pp; }
    }
    __syncthreads();
}

// parallel pool-stat reduce over COALESCED scr layout [block][256ch]:
// one block per channel ch; threads stride the gemm-block axis r at scr[r*256+ch].
__device__ inline void poolReduceC(const float* __restrict__ scr, float* __restrict__ rbuf,
                                   int gbP, int L, int ch) {
    int t = threadIdx.x;
    bool isMax = ch < 128;
    float acc = isMax ? -3.402823e38f : 0.f;
    for (int r = t; r < gbP; r += 256) {
        float v = scr[(size_t)r*256 + ch];
        acc = isMax ? fmaxf(acc, v) : (acc + v);
    }
    __shared__ float red[256];
    red[t] = acc; __syncthreads();
    for (int st = 128; st > 0; st >>= 1) {
        if (t < st) red[t] = isMax ? fmaxf(red[t], red[t+st]) : (red[t] + red[t+st]);
        __syncthreads();
    }
    if (t == 0) rbuf[L*256 + ch] = red[0];
}

__device__ const float c_invk[10] = {
    1.0f/32000.0f, 1.0f/25600.0f, 1.0f/20480.0f, 1.0f/16384.0f, 1.0f/13108.0f,
    1.0f/10487.0f, 1.0f/8390.0f,  1.0f/6712.0f,  1.0f/5370.0f,  1.0f/4296.0f };

// ---------------------------------------------------------------- init (+ layer-0 degree count + ranks)
__global__ void k_init(const int* __restrict__ eidx, int* __restrict__ esrc,
                       int* __restrict__ edst, int* __restrict__ erank,
                       const float* __restrict__ poolp,
                       float* __restrict__ rbuf, float* __restrict__ pnorm,
                       int* __restrict__ ecnt, int* __restrict__ degA,
                       int* __restrict__ tkc) {
    int b = blockIdx.x, t = threadIdx.x;
    if (b < 10) {
        rbuf[b*256 + t] = (t < 128) ? -3.402823e38f : 0.0f;
        __shared__ float red[256];
        float v = 0.0f;
        if (t < 128) { float pv = poolp[b*128 + t]; v = pv*pv; }
        red[t] = v; __syncthreads();
        for (int s = 128; s > 0; s >>= 1) { if (t < s) red[t] += red[t+s]; __syncthreads(); }
        if (t == 0) pnorm[b] = sqrtf(red[0]);
    }
    if (b == 10 && t < 16) ecnt[t] = (t == 0) ? NEDGE : 0;
    if (b == 11 && t < 64) tkc[t] = 0;
    int e = b*256 + t;
    if (e < NEDGE) {
        int d = eidx[NEDGE + e];
        esrc[e] = eidx[e]; edst[e] = d;
        erank[e] = atomicAdd(&degA[d], 1);
    }
}

// ---------------------------------------------------------------- per-chunk sums (kernel-boundary replaces barrier)
// also zeroes degN for this layer (was a pass inside k_topk)
__global__ __launch_bounds__(256) void k_presum(const int* __restrict__ deg,
                                                int* __restrict__ lbsum,
                                                int* __restrict__ degN,
                                                int n, int chunk) {
    int b = blockIdx.x, t = threadIdx.x;
    __shared__ int red[256];
    for (int i = b*256 + t; i < NMAX; i += SB*256) degN[i] = 0;
    int start = b*chunk, end = min(start + chunk, n);
    int s = 0;
    for (int i = start + t; i < end; i += 256) s += deg[i];
    red[t] = s; __syncthreads();
    for (int st = 128; st > 0; st >>= 1) { if (t < st) red[t] += red[t+st]; __syncthreads(); }
    if (t == 0) lbsum[b] = red[0];
}

// ---------------------------------------------------------------- scan + parallel pool reduce
// blocks [0,SB): scan; blocks [SB,SB+PRB): reduce previous layer's pool scratch (1 channel each)
__global__ void k_scan(const int* __restrict__ deg,
                       int* __restrict__ offs, float* __restrict__ dinv,
                       int* __restrict__ ghist, int* __restrict__ selbuf,
                       const int* __restrict__ lbsum,
                       const float* __restrict__ scr, float* __restrict__ rbuf,
                       int n, int chunk, int gbP, int prevL) {
    int b = blockIdx.x, t = threadIdx.x, lane = t & 63, wid = t >> 6;
    if (b >= SB) {
        if (gbP > 0) poolReduceC(scr, rbuf, gbP, prevL, b - SB);
        return;
    }
    __shared__ int s_excl;
    __shared__ int wsum[4];
    __shared__ int s_carry;
    __shared__ int s_sums[SB];
    if (b == 0) {
        for (int jj = t; jj < GHN; jj += 256) ghist[jj] = 0;
        if (t == 0) { selbuf[2] = 0; selbuf[5] = 0; }
    }
    if (t < SB) s_sums[t] = lbsum[t];
    __syncthreads();
    if (t == 0) {
        int excl = 0;
        for (int p = 0; p < b; p++) excl += s_sums[p];
        s_excl = excl;
    }
    __syncthreads();
    if (t == 0) s_carry = s_excl;
    __syncthreads();
    int start = b*chunk, end = min(start + chunk, n);
    for (int base = start; base < end; base += 256) {
        int i = base + t;
        int d = (i < end) ? deg[i] : 0;
        int incl = d;
        for (int off = 1; off < 64; off <<= 1) {
            int o = __shfl_up(incl, off);
            if (lane >= off) incl += o;
        }
        if (lane == 63) wsum[wid] = incl;
        __syncthreads();
        if (t == 0) { int c = s_carry; for (int w = 0; w < 4; w++) { int tmp = wsum[w]; wsum[w] = c; c += tmp; } s_carry = c; }
        __syncthreads();
        int p = wsum[wid] + incl - d;
        if (i < end) {
            offs[i] = p;
            dinv[i] = (d > 0) ? 1.0f/sqrtf((float)d) : 0.0f;
        }
        __syncthreads();
    }
}

// ---------------------------------------------------------------- slim CSR fill (rank-based, no atomics, no LDS)
__global__ __launch_bounds__(128) void k_fill(const int* __restrict__ esrc, const int* __restrict__ edst,
                                              const int* __restrict__ erank, const int* __restrict__ offs,
                                              int* __restrict__ csr, const int* __restrict__ ecnt) {
    int ec = *ecnt;
    for (int e = blockIdx.x*128 + threadIdx.x; e < ec; e += FB*128)
        csr[offs[edst[e]] + erank[e]] = esrc[e];
}

// ---------------------------------------------------------------- layer-0 fused node update
__global__ __launch_bounds__(128) void k_gather0(
    const float* __restrict__ x, const float* __restrict__ W1, const float* __restrict__ V1,
    const float* __restrict__ convb,
    const float* __restrict__ bng, const float* __restrict__ bnb,
    const float* __restrict__ bnm, const float* __restrict__ bnv,
    const float* __restrict__ poolp, const float* __restrict__ pnorm,
    const float* __restrict__ prelua,
    const int* __restrict__ offs, const int* __restrict__ deg, const float* __restrict__ dinv,
    const int* __restrict__ csr,
    float* __restrict__ AGG, float* __restrict__ score, unsigned* __restrict__ keys) {
    int v = blockIdx.x, j = threadIdx.x;
    __shared__ float red[128];
    int off = offs[v], dg = deg[v];
    float accs = 0.0f;
    for (int c = j; c < dg; c += 128) { int s = csr[off + c]; accs += x[s]*dinv[s]; }
    red[j] = accs; __syncthreads();
    for (int st = 64; st > 0; st >>= 1) { if (j < st) red[j] += red[j+st]; __syncthreads(); }
    float aggs = red[0] * dinv[v];
    __syncthreads();
    float h2 = aggs*W1[j] + x[v]*V1[j] + convb[j];
    h2 = fmaxf(h2, 0.0f);
    float scale = bng[j] / sqrtf(bnv[j] + 1e-5f);
    h2 = (h2 - bnm[j])*scale + bnb[j];
    float a = prelua[0];
    h2 = (h2 > 0.0f) ? h2 : a*h2;
    AGG[v*128 + j] = h2;
    red[j] = h2 * poolp[j]; __syncthreads();
    for (int st = 64; st > 0; st >>= 1) { if (j < st) red[j] += red[j+st]; __syncthreads(); }
    if (j == 0) {
        float sc = tanhf(red[0] / pnorm[0]);
        score[v] = sc;
        keys[v]  = orderKey(sc);
    }
}

// ---------------------------------------------------------------- generic fused gather + update + score
// neighbor loop 4-way unrolled (same accumulation order, 4 row-loads in flight)
__global__ __launch_bounds__(128) void k_gather(
    const float* __restrict__ HW, float* __restrict__ AGG,
    const int* __restrict__ offs, const int* __restrict__ deg, const float* __restrict__ dinv,
    const int* __restrict__ csr,
    const float* __restrict__ bng, const float* __restrict__ bnb,
    const float* __restrict__ bnm, const float* __restrict__ bnv,
    const float* __restrict__ poolp, const float* __restrict__ pnorm,
    const float* __restrict__ prelua,
    float* __restrict__ score, unsigned* __restrict__ keys, int layer) {
    int v = blockIdx.x, j = threadIdx.x;
    __shared__ int   s_src[128];
    __shared__ float s_dv[128];
    __shared__ float red[128];
    int off = offs[v], dg = deg[v];
    float acc = 0.0f;
    for (int base = 0; base < dg; base += 128) {
        int cnt = min(128, dg - base);
        if (j < cnt) { int s = csr[off + base + j]; s_src[j] = s; s_dv[j] = dinv[s]; }
        __syncthreads();
        int c = 0;
        for (; c + 4 <= cnt; c += 4) {
            int s0 = s_src[c], s1 = s_src[c+1], s2 = s_src[c+2], s3 = s_src[c+3];
            float d0 = s_dv[c], d1 = s_dv[c+1], d2 = s_dv[c+2], d3 = s_dv[c+3];
            float h0 = HW[(size_t)s0*128 + j];
            float h1 = HW[(size_t)s1*128 + j];
            float h2 = HW[(size_t)s2*128 + j];
            float h3 = HW[(size_t)s3*128 + j];
            acc += h0*d0; acc += h1*d1; acc += h2*d2; acc += h3*d3;
        }
        for (; c < cnt; c++) acc += HW[(size_t)s_src[c]*128 + j] * s_dv[c];
        __syncthreads();
    }
    int gj = layer*128 + j;
    float h2 = AGG[v*128 + j] + acc*dinv[v];
    h2 = fmaxf(h2, 0.0f);
    float scale = bng[gj] / sqrtf(bnv[gj] + 1e-5f);
    h2 = (h2 - bnm[gj])*scale + bnb[gj];
    float a = prelua[0];
    h2 = (h2 > 0.0f) ? h2 : a*h2;
    AGG[v*128 + j] = h2;
    red[j] = h2 * poolp[gj]; __syncthreads();
    for (int st = 64; st > 0; st >>= 1) { if (j < st) red[j] += red[j+st]; __syncthreads(); }
    if (j == 0) {
        float sc = tanhf(red[0] / pnorm[layer]);
        score[v] = sc;
        keys[v]  = orderKey(sc);
    }
}

// ---------------------------------------------------------------- fused top-k, all phases grid-parallel
__global__ __launch_bounds__(1024) void k_topk(const unsigned* __restrict__ keys,
                                               int* __restrict__ gh, int* __restrict__ selbuf,
                                               int* __restrict__ remap, int* __restrict__ keep_ids,
                                               int* __restrict__ bar, int n, int kk) {
    __shared__ int lh[2048];
    __shared__ int s_d1, s_r1, s_c1, s_dA, s_rA, s_cA, s_dB, s_ntk, s_cnt3, s_bC, s_r2, s_lowD, s_lowR;
    __shared__ int s_base, s_cur;
    int t = threadIdx.x, b = blockIdx.x, lane = t & 63;
    int* h1 = gh;
    int* h2 = gh + 2048;
    int* h3 = gh + 4096;
    int* h4 = gh + 5120;
    int* h5 = gh + 5376;

    int nR = (n + 1023) & ~1023;
    lh[t] = 0; lh[t+1024] = 0;
    __syncthreads();
    for (int i = b*1024 + t; i < nR; i += TKB*1024) {
        bool act = (i < n);
        int bin = act ? (int)(keys[i] >> 21) : 0;
        histAdd(lh, bin, act, 11);
    }
    __syncthreads();
    { int c = lh[t]; if (c) atomicAdd(&h1[t], c); c = lh[t+1024]; if (c) atomicAdd(&h1[t+1024], c); }
    gridbar(&bar[0], TKB);
    selScan2048(h1, kk, &s_d1, &s_r1, &s_c1);
    int bstar = s_d1;

    lh[t] = 0; lh[t+1024] = 0;
    __syncthreads();
    for (int i = b*1024 + t; i < nR; i += TKB*1024) {
        bool act = false; int bin = 0;
        if (i < n) { unsigned key = keys[i]; act = ((int)(key >> 21) == bstar); bin = (int)((key >> 10) & 2047); }
        histAdd(lh, act ? bin : 0, act, 11);
    }
    __syncthreads();
    { int c = lh[t]; if (c) atomicAdd(&h2[t], c); c = lh[t+1024]; if (c) atomicAdd(&h2[t+1024], c); }
    gridbar(&bar[1], TKB);
    selScan2048(h2, s_r1, &s_dA, &s_rA, &s_cA);
    unsigned top21 = ((unsigned)bstar << 11) | (unsigned)s_dA;

    lh[t] = 0;
    __syncthreads();
    for (int i = b*1024 + t; i < nR; i += TKB*1024) {
        bool act = false; int bin = 0;
        if (i < n) { unsigned key = keys[i]; act = ((key >> 10) == top21); bin = (int)(key & 1023); }
        histAdd(lh, act ? bin : 0, act, 10);
    }
    __syncthreads();
    { int c = lh[t]; if (c) atomicAdd(&h3[t], c); }
    gridbar(&bar[2], TKB);
    selScan1024(h3, s_rA, &s_dB, &s_ntk, &s_cnt3);
    unsigned thresh = (top21 << 10) | (unsigned)s_dB;

    int cut;
    if (s_cnt3 == s_ntk) {
        // no boundary tie ambiguity: keep every key == thresh (common case for continuous scores)
        cut = n - 1;
    } else {
        if (t < 256) lh[t] = 0;
        __syncthreads();
        for (int i = b*1024 + t; i < n; i += TKB*1024)
            if (keys[i] == thresh) atomicAdd(&lh[i >> 8], 1);
        __syncthreads();
        if (t < 256) { int c = lh[t]; if (c) atomicAdd(&h4[t], c); }
        gridbar(&bar[3], TKB);
        prefixSel256(lh, h4, s_ntk, &s_bC, &s_r2);
        int bC = s_bC;

        if (t < 256) lh[t] = 0;
        __syncthreads();
        for (int i = b*1024 + t; i < n; i += TKB*1024)
            if (keys[i] == thresh && (i >> 8) == bC) atomicAdd(&lh[i & 255], 1);
        __syncthreads();
        if (t < 256) { int c = lh[t]; if (c) atomicAdd(&h5[t], c); }
        gridbar(&bar[4], TKB);
        prefixSel256(lh, h5, s_r2, &s_lowD, &s_lowR);
        cut = (bC << 8) | s_lowD;
    }

    {
        int cnt = 0;
        for (int base = b*1024; base < n; base += TKB*1024) {
            int i = base + t;
            if (i < n) {
                unsigned key = keys[i];
                cnt += (key > thresh) || (key == thresh && i <= cut);
            }
        }
        lh[t] = cnt; __syncthreads();
        for (int st = 512; st > 0; st >>= 1) { if (t < st) lh[t] += lh[t+st]; __syncthreads(); }
        if (t == 0) { s_base = atomicAdd(&selbuf[5], lh[0]); s_cur = 0; }
        __syncthreads();
        for (int base = b*1024; base < n; base += TKB*1024) {
            int i = base + t;
            bool keep = false;
            if (i < n) {
                unsigned key = keys[i];
                keep = (key > thresh) || (key == thresh && i <= cut);
            }
            unsigned long long m = __ballot(keep);
            int wcnt = __popcll(m);
            int wbase = 0;
            if (lane == 0 && wcnt) wbase = atomicAdd(&s_cur, wcnt);
            wbase = __shfl(wbase, 0);
            if (keep) {
                int slot = s_base + wbase + __popcll(m & ((1ULL << lane) - 1));
                remap[i] = slot; keep_ids[slot] = i;
            } else if (i < n) remap[i] = -1;
        }
    }
}

// ---------------------------------------------------------------- fused pool stats + next-layer GEMM + edge compact
// split-K: 256 thr, half h computes kk in [h*64,(h+1)*64); partials combined via LDS.
// W/V bytes per block unchanged vs 128-thr version; serial kk chain halved; 4 waves/block.
// blocks [gb,gb+EBLK): edge remap/compact (+next-layer degree/rank)
template<int TGRB>
__global__ __launch_bounds__(256) void k_poolgemm(
        const float* __restrict__ AGGc, const float* __restrict__ score,
        const int* __restrict__ keep_ids, const int* __restrict__ remap,
        float* __restrict__ scr,
        const int* __restrict__ esrcP, const int* __restrict__ edstP,
        int* __restrict__ esrcN, int* __restrict__ edstN, int* __restrict__ erankN,
        const int* __restrict__ ecntP, int* __restrict__ ecntN, int* __restrict__ degN,
        const float* __restrict__ W, const float* __restrict__ V, const float* __restrict__ bias,
        float* __restrict__ HW, float* __restrict__ AGGn, int k, int gb, int do_gemm) {
    constexpr int THTS = TGRB + 4;
    int b = blockIdx.x, t = threadIdx.x;
    __shared__ __align__(16) float ht[128*THTS];        // TGRB=16: 10.2KB, TGRB=8: 6.1KB
    __shared__ __align__(16) float part[2*TGRB*128];    // TGRB=16: 16KB,  TGRB=8: 8KB
    if (b < gb) {
        int tt = t & 127, hf = t >> 7;
        constexpr int RH = TGRB/2;
        int v0 = b * TGRB;
        float mx = -3.402823e38f, sm = 0.f;
        #pragma unroll
        for (int it = 0; it < RH; it++) {
            int r = v0 + hf*RH + it;
            bool valid = (r < k);
            int vv = keep_ids[valid ? r : (k - 1)];
            float val = AGGc[(size_t)vv*128 + tt] * score[vv];
            if (!valid) val = 0.f;
            ht[tt*THTS + hf*RH + it] = val;
            if (valid) { mx = fmaxf(mx, val); sm += val; }
        }
        part[hf*128 + tt]       = mx;
        part[256 + hf*128 + tt] = sm;
        __syncthreads();
        if (t < 128) {
            scr[b*256 + t]       = fmaxf(part[t], part[128 + t]);
            scr[b*256 + 128 + t] = part[256 + t] + part[384 + t];
        }
        if (!do_gemm) return;
        float accW[TGRB], accV[TGRB];
        #pragma unroll
        for (int r = 0; r < TGRB; r++) { accW[r] = 0.0f; accV[r] = 0.0f; }
        int kk0 = hf * 64, kk1 = kk0 + 64;
        #pragma unroll 4
        for (int kk = kk0; kk < kk1; kk++) {
            float mw = W[kk*128 + tt];
            float mv = V[kk*128 + tt];
            const float* hp = &ht[kk*THTS];
            #pragma unroll
            for (int r4 = 0; r4 < TGRB; r4 += 4) {
                float4 hq = *(const float4*)(hp + r4);
                accW[r4+0] += hq.x*mw;  accV[r4+0] += hq.x*mv;
                accW[r4+1] += hq.y*mw;  accV[r4+1] += hq.y*mv;
                accW[r4+2] += hq.z*mw;  accV[r4+2] += hq.z*mv;
                accW[r4+3] += hq.w*mw;  accV[r4+3] += hq.w*mv;
            }
        }
        __syncthreads();   // stats reads done; both halves done with kk loop
        if (hf == 1) {
            #pragma unroll
            for (int r = 0; r < TGRB; r++) {
                part[(2*r+0)*128 + tt] = accW[r];
                part[(2*r+1)*128 + tt] = accV[r];
            }
        }
        __syncthreads();
        if (hf == 0) {
            float bb = bias[tt];
            #pragma unroll
            for (int r = 0; r < TGRB; r++) {
                int v = v0 + r;
                if (v >= k) break;
                float w2 = accW[r] + part[(2*r+0)*128 + tt];
                float v2 = accV[r] + part[(2*r+1)*128 + tt];
                HW[(size_t)v*128 + tt]   = w2;
                AGGn[(size_t)v*128 + tt] = v2 + bb;
            }
        }
    } else {
        int eb = b - gb, lane = t & 63;
        int ec = *ecntP;
        int* red = (int*)ht;
        __shared__ int s_base, s_cur;
        int cnt = 0;
        for (int base = eb*256; base < ec; base += EBLK*256) {
            int e = base + t;
            if (e < ec) {
                int ns = remap[esrcP[e]], nd = remap[edstP[e]];
                cnt += (ns >= 0 && nd >= 0);
            }
        }
        red[t] = cnt; __syncthreads();
        for (int st = 128; st > 0; st >>= 1) { if (t < st) red[t] += red[t+st]; __syncthreads(); }
        if (t == 0) { s_base = atomicAdd(ecntN, red[0]); s_cur = 0; }
        __syncthreads();
        for (int base = eb*256; base < ec; base += EBLK*256) {
            int e = base + t;
            bool keep = false; int ns = 0, nd = 0;
            if (e < ec) {
                ns = remap[esrcP[e]]; nd = remap[edstP[e]];
                keep = (ns >= 0 && nd >= 0);
            }
            unsigned long long m = __ballot(keep);
            int wcnt = __popcll(m);
            int wbase = 0;
            if (lane == 0 && wcnt) wbase = atomicAdd(&s_cur, wcnt);
            wbase = __shfl(wbase, 0);
            if (keep) {
                int pos = s_base + wbase + __popcll(m & ((1ULL << lane) - 1));
                esrcN[pos] = ns; edstN[pos] = nd;
                erankN[pos] = atomicAdd(&degN[nd], 1);
            }
        }
    }
}

// ---------------------------------------------------------------- final-layer scratch reduce (parallel, 1 channel/block)
__global__ __launch_bounds__(256) void k_pred(const float* __restrict__ scr, float* __restrict__ rbuf,
                                              int gbP, int L) {
    poolReduceC(scr, rbuf, gbP, L, blockIdx.x);
}

// ---------------------------------------------------------------- MLP head
__global__ __launch_bounds__(320) void k_lin1(const float* __restrict__ rbuf,
                                              const float* __restrict__ w1,
                                              float* __restrict__ z1part) {
    int b = blockIdx.x, t = threadIdx.x;
    int j = t*4;
    float4 acc = make_float4(0.f, 0.f, 0.f, 0.f);
    int i0 = b*40;
    for (int r = 0; r < 40; r++) {
        int i = i0 + r;
        float rv = rbuf[i];
        if (i & 128) rv *= c_invk[i >> 8];
        float4 w = *(const float4*)(w1 + (size_t)i*1280 + j);
        acc.x += rv*w.x; acc.y += rv*w.y; acc.z += rv*w.z; acc.w += rv*w.w;
    }
    *(float4*)(z1part + b*1280 + j) = acc;
}

__global__ __launch_bounds__(320) void k_lin2(const float* __restrict__ z1part,
                                              const float* __restrict__ b1,
                                              const float* __restrict__ w2, const float* __restrict__ b2,
                                              const float* __restrict__ prelua, float* __restrict__ out) {
    int t = threadIdx.x, lane = t & 63, wid = t >> 6;
    float a = prelua[0];
    int j = t*4;
    float4 acc = make_float4(0.f, 0.f, 0.f, 0.f);
    for (int p = 0; p < LIN1B; p++) {
        float4 v = *(const float4*)(z1part + p*1280 + j);
        acc.x += v.x; acc.y += v.y; acc.z += v.z; acc.w += v.w;
    }
    float4 bb = *(const float4*)(b1 + j);
    float z0 = acc.x + bb.x; z0 = z0 > 0.f ? z0 : a*z0;
    float z1 = acc.y + bb.y; z1 = z1 > 0.f ? z1 : a*z1;
    float z2 = acc.z + bb.z; z2 = z2 > 0.f ? z2 : a*z2;
    float z3 = acc.w + bb.w; z3 = z3 > 0.f ? z3 : a*z3;
    float s[8];
    #pragma unroll
    for (int o = 0; o < 8; o++)
        s[o] = z0*w2[(j+0)*8+o] + z1*w2[(j+1)*8+o] + z2*w2[(j+2)*8+o] + z3*w2[(j+3)*8+o];
    #pragma unroll
    for (int off = 32; off > 0; off >>= 1)
        #pragma unroll
        for (int o = 0; o < 8; o++) s[o] += __shfl_down(s[o], off);
    __shared__ float sred[5][8];
    if (lane == 0)
        for (int o = 0; o < 8; o++) sred[wid][o] = s[o];
    __syncthreads();
    if (t == 0) {
        float zo[8];
        for (int o = 0; o < 8; o++) {
            float z = sred[0][o]+sred[1][o]+sred[2][o]+sred[3][o]+sred[4][o] + b2[o];
            zo[o] = z > 0.f ? z : a*z;
        }
        float mn = zo[0];
        for (int o = 1; o < 8; o++) mn = fminf(mn, zo[o]);
        float v[8], mx = -3.402823e38f;
        for (int o = 0; o < 8; o++) { v[o] = zo[o] - mn; mx = fmaxf(mx, v[o]); }
        float sm = 0.f;
        for (int o = 0; o < 8; o++) { v[o] = v[o] / mx; sm += v[o]; }
        for (int o = 0; o < 8; o++) out[o] = v[o] / sm;
    }
}

// ---------------------------------------------------------------- launch
extern "C" void kernel_launch(void* const* d_in, const int* in_sizes, int n_in,
                              void* d_out, int out_size, void* d_ws, size_t ws_size,
                              hipStream_t stream) {
    const float* x      = (const float*)d_in[0];
    const int*   eidx   = (const int*)  d_in[1];
    const float* W1     = (const float*)d_in[2];
    const float* V1     = (const float*)d_in[3];
    const float* Ws     = (const float*)d_in[4];
    const float* Vs     = (const float*)d_in[5];
    const float* convb  = (const float*)d_in[6];
    const float* bng    = (const float*)d_in[7];
    const float* bnb    = (const float*)d_in[8];
    const float* bnm    = (const float*)d_in[9];
    const float* bnv    = (const float*)d_in[10];
    const float* poolp  = (const float*)d_in[11];
    const float* prelua = (const float*)d_in[12];
    const float* w1     = (const float*)d_in[13];
    const float* b1     = (const float*)d_in[14];
    const float* w2     = (const float*)d_in[15];
    const float* b2     = (const float*)d_in[16];
    float* out = (float*)d_out;

    float* wsf  = (float*)d_ws;
    float* aggA   = wsf;                          // NMAX*128
    float* aggB   = aggA  + (size_t)NMAX*128;
    float* HW     = aggB  + (size_t)NMAX*128;
    float* dinv   = HW    + (size_t)NMAX*128;
    float* score  = dinv  + NMAX;
    float* rbuf   = score + NMAX;
    float* pnorm  = rbuf  + 2560;
    float* z1part = pnorm + 16;                   // LIN1B*1280
    float* scr    = z1part + LIN1B*1280;          // GBMAX*256 (coalesced: [block][256ch])
    unsigned* keys = (unsigned*)(scr + (size_t)GBMAX*256);
    int* esrcA  = (int*)(keys + NMAX);
    int* edstA  = esrcA + NEDGE;
    int* erankA = edstA + NEDGE;
    int* esrcB  = erankA + NEDGE;
    int* edstB  = esrcB + NEDGE;
    int* erankB = edstB + NEDGE;
    int* csr    = erankB + NEDGE;
    int* degA   = csr   + NEDGE;
    int* degB   = degA  + NMAX;
    int* ghist  = degB  + NMAX;                   // GHN
    int* offs   = ghist + GHN;
    int* remap  = offs  + NMAX;
    int* keep_ids = remap + NMAX;
    int* lbsum  = keep_ids + NMAX;                // SB*2
    int* ecnt   = lbsum + SB*2;                   // 16
    int* selbuf = ecnt  + 16;                     // 16
    int* tkc    = selbuf + 16;                    // 64

    static const int NS[10] = {40000,32000,25600,20480,16384,13108,10487,8390,6712,5370};
    static const int KS[10] = {32000,25600,20480,16384,13108,10487,8390,6712,5370,4296};
    // per-layer gemm-rows: 16 while grid stays large, 8 when grid would starve
    static const int GRBS[10] = {16,16,16,16,8,8,8,8,8,8};

    int gbs[10];
    for (int i = 0; i < 10; i++) gbs[i] = (KS[i] + GRBS[i] - 1) / GRBS[i];

    hipMemsetAsync(degA, 0, (size_t)NMAX*sizeof(int), stream);
    k_init<<<2500, 256, 0, stream>>>(eidx, esrcA, edstA, erankA, poolp, rbuf, pnorm,
                                     ecnt, degA, tkc);

    for (int i = 0; i < 10; i++) {
        int n = NS[i], k = KS[i];
        int chunk = (n + SB - 1) / SB;
        int* esrcP  = (i & 1) ? esrcB  : esrcA;
        int* edstP  = (i & 1) ? edstB  : edstA;
        int* erankP = (i & 1) ? erankB : erankA;
        int* esrcN  = (i & 1) ? esrcA  : esrcB;
        int* edstN  = (i & 1) ? edstA  : edstB;
        int* erankN = (i & 1) ? erankA : erankB;
        int* degP   = (i & 1) ? degB : degA;
        int* degN   = (i & 1) ? degA : degB;
        float* AGGc = (i & 1) ? aggB : aggA;      // current layer features
        float* AGGn = (i & 1) ? aggA : aggB;      // next layer buffer

        int gbP = (i == 0) ? 0 : gbs[i-1];
        k_presum<<<SB, 256, 0, stream>>>(degP, lbsum, degN, n, chunk);
        k_scan<<<SB + PRB, 256, 0, stream>>>(degP, offs, dinv, ghist, selbuf,
                                             lbsum, scr, rbuf, n, chunk,
                                             gbP, i - 1);

        k_fill<<<FB, 128, 0, stream>>>(esrcP, edstP, erankP, offs, csr, &ecnt[i]);

        if (i == 0) {
            k_gather0<<<n, 128, 0, stream>>>(x, W1, V1, convb,
                                             bng, bnb, bnm, bnv, poolp, pnorm, prelua,
                                             offs, degP, dinv, csr, AGGc, score, keys);
        } else {
            k_gather<<<n, 128, 0, stream>>>(HW, AGGc, offs, degP, dinv, csr,
                                            bng, bnb, bnm, bnv, poolp, pnorm, prelua,
                                            score, keys, i);
        }

        k_topk<<<TKB, 1024, 0, stream>>>(keys, ghist, selbuf,
                                         remap, keep_ids, tkc + i*5, n, k);

        int gb = gbs[i];
        int do_gemm = (i < 9);
        int grid = gb + (do_gemm ? EBLK : 0);
        // gemm computes layer i+1: weights Ws[(i+1)-1] = Ws + i*16384, bias convb+(i+1)*128
        if (GRBS[i] == 16) {
            k_poolgemm<16><<<grid, 256, 0, stream>>>(AGGc, score, keep_ids, remap, scr,
                                                     esrcP, edstP, esrcN, edstN, erankN,
                                                     &ecnt[i], &ecnt[i+1], degN,
                                                     Ws + (size_t)min(i,8)*16384,
                                                     Vs + (size_t)min(i,8)*16384,
                                                     convb + min(i+1,9)*128,
                                                     HW, AGGn, k, gb, do_gemm);
        } else {
            k_poolgemm<8><<<grid, 256, 0, stream>>>(AGGc, score, keep_ids, remap, scr,
                                                    esrcP, edstP, esrcN, edstN, erankN,
                                                    &ecnt[i], &ecnt[i+1], degN,
                                                    Ws + (size_t)min(i,8)*16384,
                                                    Vs + (size_t)min(i,8)*16384,
                                                    convb + min(i+1,9)*128,
                                                    HW, AGGn, k, gb, do_gemm);
        }
    }

    k_pred<<<PRB, 256, 0, stream>>>(scr, rbuf, gbs[9], 9);
    k_lin1<<<LIN1B, 320, 0, stream>>>(rbuf, w1, z1part);
    k_lin2<<<1, 320, 0, stream>>>(z1part, b1, w2, b2, prelua, out);
}